// Round 2
// baseline (7493.237 us; speedup 1.0000x reference)
//
#include <hip/hip_runtime.h>
#include <math.h>

#define BT 16
#define CCH 256
#define IH 96
#define IW 96
#define HW (IH*IW)            // 9216
#define DK 64

static const long long WIN   = (long long)BT * HW * DK;   // 9,437,184 floats (one head, all bt)
static const long long NFULL = 4 * WIN;                    // 37,748,736 floats

// ---------------- fused 1x1-conv projection + window layout
// Computes out[bt, n, ch*P^2 + py*P + px] = sum_c W[head*64+ch, c] x[bt, c, y, x] + b
// where y = (n/SIDE)*P + py, x = (n%SIDE)*P + px.
// Block: 64 output channels x 128 window-ordered pixels; grid (72, 1, BT).
template<int P, int LOGP>
__global__ __launch_bounds__(256) void proj_win_kernel(const float* __restrict__ x,
        const float* __restrict__ W, const float* __restrict__ bias,
        float* __restrict__ out, int head)
{
    constexpr int SIDE = 96 / P;
    constexpr int NWIN = SIDE * SIDE;
    constexpr int DLEN = DK * P * P;
    constexpr int PP = P * P;
    __shared__ float Xs[16][128];
    __shared__ float Wsh[64][16];
    int tid = threadIdx.x;
    int g0 = blockIdx.x * 128;          // window-ordered global pixel base
    int bt = blockIdx.z;
    int o0 = head * DK;
    int sc = tid & 31, orow = tid >> 5;

    // precompute source pixel offsets for the 2 staging slots (16ch x 128px per K-chunk)
    int rowslot[2], spix0[2];
    #pragma unroll
    for (int l = 0; l < 2; l++) {
        int flat = l * 1024 + tid * 4;
        int row = flat >> 7, p4 = flat & 127;
        rowslot[l] = row;
        int g = g0 + p4;
        int n = g >> (2 * LOGP);
        int pyx = g & (PP - 1);
        int py = pyx >> LOGP, px = pyx & (P - 1);
        int oh = n / SIDE, ow = n - oh * SIDE;
        spix0[l] = (oh * P + py) * IW + ow * P + px;
    }

    float acc[8][4] = {};
    const float* xb = x + (long long)bt * CCH * HW;
    for (int kc = 0; kc < CCH; kc += 16) {
        #pragma unroll
        for (int l = 0; l < 2; l++) {
            const float* src = xb + (long long)(kc + rowslot[l]) * HW + spix0[l];
            int p4 = (l * 1024 + tid * 4) & 127;
            if constexpr (P == 2) {
                float2 a = *(const float2*)(src);
                float2 b = *(const float2*)(src + IW);
                Xs[rowslot[l]][p4 + 0] = a.x; Xs[rowslot[l]][p4 + 1] = a.y;
                Xs[rowslot[l]][p4 + 2] = b.x; Xs[rowslot[l]][p4 + 3] = b.y;
            } else {
                float4 v = *(const float4*)(src);
                *(float4*)(&Xs[rowslot[l]][p4]) = v;
            }
        }
        {
            int row = tid >> 2, c4 = (tid & 3) * 4;
            float4 wv = *(const float4*)(W + (long long)(o0 + row) * CCH + kc + c4);
            *(float4*)(&Wsh[row][c4]) = wv;
        }
        __syncthreads();
        #pragma unroll
        for (int kk = 0; kk < 16; kk++) {
            float4 xv = *(const float4*)(&Xs[kk][sc * 4]);
            #pragma unroll
            for (int r = 0; r < 8; r++) {
                float wv = Wsh[orow * 8 + r][kk];
                acc[r][0] += wv * xv.x; acc[r][1] += wv * xv.y;
                acc[r][2] += wv * xv.z; acc[r][3] += wv * xv.w;
            }
        }
        __syncthreads();
    }
    // epilogue: window-contiguous float4 stores
    int g = g0 + sc * 4;
    int n = g >> (2 * LOGP);
    int pyx = g & (PP - 1);
    long long base = ((long long)bt * NWIN + n) * DLEN + pyx;
    #pragma unroll
    for (int r = 0; r < 8; r++) {
        int ch = orow * 8 + r;
        float bv = bias[o0 + ch];
        float4 res;
        res.x = acc[r][0] + bv; res.y = acc[r][1] + bv;
        res.z = acc[r][2] + bv; res.w = acc[r][3] + bv;
        *(float4*)(&out[base + (long long)ch * PP]) = res;
    }
}

// ---------------- QK^T 64x64 tile (optional split-K -> fp32 partial tiles)
// scores/partial are indexed with CHUNK-LOCAL bt; qw/kw with global bt = bt0 + local.
__global__ __launch_bounds__(256) void qk_kernel(const float* __restrict__ qw,
    const float* __restrict__ kw, float* __restrict__ scores,
    float* __restrict__ partial, int nw, int dlen, float scale, int ksplit,
    int tspan, int bt0)
{
    __shared__ float Qs[64][20];
    __shared__ float Ks[64][20];
    int tid = threadIdx.x;
    int m0 = blockIdx.x * 64;
    int n0 = blockIdx.y * 64;
    int btl = blockIdx.z / ksplit;
    int kidx = blockIdx.z - btl * ksplit;
    int bt = bt0 + btl;
    int dchunk = dlen / ksplit;
    long long kbase = (long long)kidx * dchunk;
    int tx = tid & 15, ty = tid >> 4;
    float acc[4][4] = {};
    const float* qb = qw + (long long)bt * nw * dlen;
    const float* kb = kw + (long long)bt * nw * dlen;
    int lr = tid >> 2, lc = (tid & 3) * 4;
    for (int kc = 0; kc < dchunk; kc += 16) {
        float4 qv = make_float4(0.f, 0.f, 0.f, 0.f);
        if (n0 + lr < nw) qv = *(const float4*)(qb + (long long)(n0 + lr) * dlen + kbase + kc + lc);
        float4 kv = make_float4(0.f, 0.f, 0.f, 0.f);
        if (m0 + lr < nw) kv = *(const float4*)(kb + (long long)(m0 + lr) * dlen + kbase + kc + lc);
        *(float4*)(&Qs[lr][lc]) = qv;
        *(float4*)(&Ks[lr][lc]) = kv;
        __syncthreads();
        #pragma unroll
        for (int kk = 0; kk < 16; kk++) {
            float a0 = Qs[ty*4+0][kk], a1 = Qs[ty*4+1][kk];
            float a2 = Qs[ty*4+2][kk], a3 = Qs[ty*4+3][kk];
            float b0 = Ks[tx+ 0][kk], b1 = Ks[tx+16][kk];
            float b2 = Ks[tx+32][kk], b3 = Ks[tx+48][kk];
            acc[0][0] += a0*b0; acc[0][1] += a0*b1; acc[0][2] += a0*b2; acc[0][3] += a0*b3;
            acc[1][0] += a1*b0; acc[1][1] += a1*b1; acc[1][2] += a1*b2; acc[1][3] += a1*b3;
            acc[2][0] += a2*b0; acc[2][1] += a2*b1; acc[2][2] += a2*b2; acc[2][3] += a2*b3;
            acc[3][0] += a3*b0; acc[3][1] += a3*b1; acc[3][2] += a3*b2; acc[3][3] += a3*b3;
        }
        __syncthreads();
    }
    if (ksplit == 1) {
        #pragma unroll
        for (int i = 0; i < 4; i++) {
            int r = n0 + ty * 4 + i;
            if (r >= nw) continue;
            #pragma unroll
            for (int j = 0; j < 4; j++) {
                int c = m0 + tx + 16 * j;
                if (c < nw)
                    scores[((long long)btl * nw + r) * nw + c] = acc[i][j] * scale;
            }
        }
    } else {
        #pragma unroll
        for (int i = 0; i < 4; i++)
            #pragma unroll
            for (int j = 0; j < 4; j++)
                partial[(((long long)btl * ksplit + kidx) * tspan + (n0 + ty*4 + i)) * tspan + (m0 + tx + 16*j)] = acc[i][j];
    }
}

__global__ __launch_bounds__(256) void qk_reduce_kernel(const float* __restrict__ partial,
    float* __restrict__ scores, int nw, int tspan, int ksplit, float scale, int btc)
{
    long long idx = (long long)blockIdx.x * 256 + threadIdx.x;
    if (idx >= (long long)btc * nw * nw) return;
    int m = (int)(idx % nw);
    long long t = idx / nw;
    int n = (int)(t % nw);
    int btl = (int)(t / nw);
    float s = 0.f;
    for (int k = 0; k < ksplit; k++)
        s += partial[(((long long)btl * ksplit + k) * tspan + n) * tspan + m];
    scores[((long long)btl * nw + n) * nw + m] = s * scale;
}

// ---------------- row softmax (fp32 scores in-place), chunk-local bt
__global__ __launch_bounds__(256) void softmax_kernel(float* __restrict__ scores, int nw)
{
    __shared__ float red[8];
    int n = blockIdx.x, btl = blockIdx.y;
    float* row = scores + ((long long)btl * nw + n) * nw;
    int tid = threadIdx.x;
    float vals[9];
    float lmax = -3e38f;
    #pragma unroll
    for (int it = 0; it < 9; it++) {
        int m = tid + it * 256;
        if (m < nw) { vals[it] = row[m]; lmax = fmaxf(lmax, vals[it]); }
        else vals[it] = -3e38f;
    }
    #pragma unroll
    for (int o = 32; o > 0; o >>= 1) lmax = fmaxf(lmax, __shfl_down(lmax, o, 64));
    if ((tid & 63) == 0) red[tid >> 6] = lmax;
    __syncthreads();
    float rmax = fmaxf(fmaxf(red[0], red[1]), fmaxf(red[2], red[3]));
    __syncthreads();
    float lsum = 0.f;
    #pragma unroll
    for (int it = 0; it < 9; it++) {
        int m = tid + it * 256;
        if (m < nw) { vals[it] = __expf(vals[it] - rmax); lsum += vals[it]; }
    }
    #pragma unroll
    for (int o = 32; o > 0; o >>= 1) lsum += __shfl_down(lsum, o, 64);
    if ((tid & 63) == 0) red[tid >> 6] = lsum;
    __syncthreads();
    float rsum = red[0] + red[1] + red[2] + red[3];
    float inv = 1.f / rsum;
    #pragma unroll
    for (int it = 0; it < 9; it++) {
        int m = tid + it * 256;
        if (m < nw) row[m] = vals[it] * inv;
    }
}

// ---------------- P @ V  64(n) x 64(d) tile; scores chunk-local, vw/yw global bt
__global__ __launch_bounds__(256) void pv_kernel(const float* __restrict__ p,
    const float* __restrict__ vw, float* __restrict__ yw, int nw, int dlen, int bt0)
{
    __shared__ float Ps[64][20];
    __shared__ float Vs[16][68];
    int tid = threadIdx.x;
    int d0 = blockIdx.x * 64;
    int n0 = blockIdx.y * 64;
    int btl = blockIdx.z;
    int bt = bt0 + btl;
    int tx = tid & 15, ty = tid >> 4;
    float acc[4][4] = {};
    const float* pb = p + (long long)btl * nw * nw;
    const float* vb = vw + (long long)bt * nw * dlen;
    int plr = tid >> 2, plc = (tid & 3) * 4;
    int vlr = tid >> 4, vlc = (tid & 15) * 4;
    for (int mc = 0; mc < nw; mc += 16) {
        float4 pv4 = make_float4(0.f, 0.f, 0.f, 0.f);
        if (n0 + plr < nw) {
            int mbase = mc + plc;
            if (mbase + 3 < nw) {
                pv4 = *(const float4*)(pb + (long long)(n0 + plr) * nw + mbase);
            } else {
                float tmp[4] = {0.f, 0.f, 0.f, 0.f};
                for (int e = 0; e < 4; e++)
                    if (mbase + e < nw) tmp[e] = pb[(long long)(n0 + plr) * nw + mbase + e];
                pv4 = make_float4(tmp[0], tmp[1], tmp[2], tmp[3]);
            }
        }
        *(float4*)(&Ps[plr][plc]) = pv4;
        float4 vv = make_float4(0.f, 0.f, 0.f, 0.f);
        if (mc + vlr < nw) vv = *(const float4*)(vb + (long long)(mc + vlr) * dlen + d0 + vlc);
        *(float4*)(&Vs[vlr][vlc]) = vv;
        __syncthreads();
        #pragma unroll
        for (int mm = 0; mm < 16; mm++) {
            float4 bv = *(const float4*)(&Vs[mm][tx * 4]);
            float a0 = Ps[ty*4+0][mm], a1 = Ps[ty*4+1][mm];
            float a2 = Ps[ty*4+2][mm], a3 = Ps[ty*4+3][mm];
            acc[0][0] += a0*bv.x; acc[0][1] += a0*bv.y; acc[0][2] += a0*bv.z; acc[0][3] += a0*bv.w;
            acc[1][0] += a1*bv.x; acc[1][1] += a1*bv.y; acc[1][2] += a1*bv.z; acc[1][3] += a1*bv.w;
            acc[2][0] += a2*bv.x; acc[2][1] += a2*bv.y; acc[2][2] += a2*bv.z; acc[2][3] += a2*bv.w;
            acc[3][0] += a3*bv.x; acc[3][1] += a3*bv.y; acc[3][2] += a3*bv.z; acc[3][3] += a3*bv.w;
        }
        __syncthreads();
    }
    #pragma unroll
    for (int i = 0; i < 4; i++) {
        int r = n0 + ty * 4 + i;
        if (r >= nw) continue;
        float4 res;
        res.x = acc[i][0]; res.y = acc[i][1]; res.z = acc[i][2]; res.w = acc[i][3];
        *(float4*)(yw + ((long long)bt * nw + r) * dlen + d0 + tx * 4) = res;
    }
}

// ---------------- unwindow scatter back to att[bt, c, h, w] (att == d_out)
template<int P>
__global__ __launch_bounds__(256) void unwindow_kernel(const float* __restrict__ yw,
    float* __restrict__ att, int head)
{
    constexpr int SIDE = 96 / P;
    constexpr int DLEN = DK * P * P;
    long long idx = (long long)blockIdx.x * 256 + threadIdx.x;
    if (idx >= (long long)BT * DK * HW) return;
    int x = (int)(idx % IW);
    long long t = idx / IW;
    int y = (int)(t % IH); t /= IH;
    int ch = (int)(t % DK);
    int bt = (int)(t / DK);
    int oh = y / P, py = y & (P - 1), ow = x / P, px = x & (P - 1);
    int n = oh * SIDE + ow;
    int dd = (ch * P + py) * P + px;
    att[(((long long)(bt * CCH + head * DK + ch)) * IH + y) * IW + x] =
        yw[((long long)bt * (SIDE * SIDE) + n) * DLEN + dd];
}

// ---------------- 3x3 SAME conv + bias + LeakyReLU(0.2); att=d_out -> convout=ws
__global__ __launch_bounds__(256) void conv_kernel(const float* __restrict__ att,
    const float* __restrict__ Wo, const float* __restrict__ bo, float* __restrict__ convout)
{
    __shared__ float As[16][3][98];
    __shared__ float Wsh[64][16][9];
    int tid = threadIdx.x;
    int yy = blockIdx.x;
    int o0 = blockIdx.y * 64;
    int bt = blockIdx.z;
    int pg = tid & 15, og = tid >> 4;
    int px0 = pg * 6;
    float acc[4][6] = {};
    for (int cc = 0; cc < CCH; cc += 16) {
        for (int idx = tid; idx < 16 * 3 * 98; idx += 256) {
            int xx = idx % 98;
            int t = idx / 98;
            int dy = t % 3;
            int c = t / 3;
            int ya = yy + dy - 1;
            float v = 0.f;
            if (ya >= 0 && ya < IH && xx >= 1 && xx <= 96)
                v = att[((long long)(bt * CCH + cc + c) * IH + ya) * IW + (xx - 1)];
            As[c][dy][xx] = v;
        }
        for (int idx = tid; idx < 64 * 16 * 9; idx += 256) {
            int t9 = idx % 9;
            int t = idx / 9;
            int c = t % 16;
            int oo = t / 16;
            Wsh[oo][c][t9] = Wo[((long long)(o0 + oo) * CCH + cc + c) * 9 + t9];
        }
        __syncthreads();
        for (int c = 0; c < 16; c++) {
            float a[3][8];
            #pragma unroll
            for (int dy = 0; dy < 3; dy++)
                #pragma unroll
                for (int xx = 0; xx < 8; xx++)
                    a[dy][xx] = As[c][dy][px0 + xx];
            #pragma unroll
            for (int r = 0; r < 4; r++) {
                const float* wrow = &Wsh[og * 4 + r][c][0];
                float w[9];
                #pragma unroll
                for (int t9 = 0; t9 < 9; t9++) w[t9] = wrow[t9];
                #pragma unroll
                for (int dy = 0; dy < 3; dy++)
                    #pragma unroll
                    for (int dx = 0; dx < 3; dx++)
                        #pragma unroll
                        for (int q = 0; q < 6; q++)
                            acc[r][q] += w[dy * 3 + dx] * a[dy][q + dx];
            }
        }
        __syncthreads();
    }
    #pragma unroll
    for (int r = 0; r < 4; r++) {
        int o = o0 + og * 4 + r;
        float bv = bo[o];
        #pragma unroll
        for (int q = 0; q < 6; q++) {
            float v = acc[r][q] + bv;
            convout[((long long)(bt * CCH + o) * IH + yy) * IW + px0 + q] = v >= 0.f ? v : 0.2f * v;
        }
    }
}

// ---------------- per-head host driver
template<int P, int LOGP>
static void run_head(const float* x, const float* x1,
                     const float* Wq, const float* bq,
                     const float* Wk, const float* bk,
                     const float* Wv, const float* bv,
                     float* qw, float* kw, float* vw, float* yw,
                     float* scores, float* partial, float* att,
                     size_t sbud, int head, int ks, hipStream_t stream)
{
    constexpr int SIDE = 96 / P;
    constexpr int NWIN = SIDE * SIDE;
    constexpr int DLEN = DK * P * P;
    int nw = NWIN, dlen = DLEN;
    float scale = 1.0f / sqrtf((float)dlen);
    int nt = (nw + 63) / 64;
    int tspan = nt * 64;
    dim3 blk(256);

    proj_win_kernel<P, LOGP><<<dim3(72, 1, BT), blk, 0, stream>>>(x,  Wq, bq, qw, head);
    proj_win_kernel<P, LOGP><<<dim3(72, 1, BT), blk, 0, stream>>>(x1, Wk, bk, kw, head);
    proj_win_kernel<P, LOGP><<<dim3(72, 1, BT), blk, 0, stream>>>(x1, Wv, bv, vw, head);

    int btc = BT;
    while (btc > 1 && (size_t)btc * nw * nw * sizeof(float) > sbud) btc >>= 1;

    for (int bt0 = 0; bt0 < BT; bt0 += btc) {
        qk_kernel<<<dim3(nt, nt, btc * ks), blk, 0, stream>>>(qw, kw, scores, partial,
                                                              nw, dlen, scale, ks, tspan, bt0);
        if (ks > 1) {
            long long tot = (long long)btc * nw * nw;
            qk_reduce_kernel<<<(unsigned)((tot + 255) / 256), blk, 0, stream>>>(
                partial, scores, nw, tspan, ks, scale, btc);
        }
        softmax_kernel<<<dim3(nw, btc), blk, 0, stream>>>(scores, nw);
        pv_kernel<<<dim3(dlen / 64, nt, btc), blk, 0, stream>>>(scores, vw, yw, nw, dlen, bt0);
    }
    unwindow_kernel<P><<<36864, blk, 0, stream>>>(yw, att, head);
}

extern "C" void kernel_launch(void* const* d_in, const int* in_sizes, int n_in,
                              void* d_out, int out_size, void* d_ws, size_t ws_size,
                              hipStream_t stream) {
    const float* x  = (const float*)d_in[0];
    const float* x1 = (const float*)d_in[1];
    const float* Wq = (const float*)d_in[2];
    const float* bq = (const float*)d_in[3];
    const float* Wk = (const float*)d_in[4];
    const float* bk = (const float*)d_in[5];
    const float* Wv = (const float*)d_in[6];
    const float* bv = (const float*)d_in[7];
    const float* Wo = (const float*)d_in[8];
    const float* bo = (const float*)d_in[9];
    float* out = (float*)d_out;

    float* ws = (float*)d_ws;
    float* qw = ws;                 // WIN
    float* kw = ws + WIN;           // WIN
    float* vw = ws + 2 * WIN;       // WIN
    float* yw = ws + 3 * WIN;       // WIN (also split-K partial)
    float* convout = ws;            // overlays qw..yw (dead when conv runs)
    float* scores  = ws + NFULL;    // adaptive size
    float* partial = yw;
    float* att = out;               // attention output staged in d_out

    size_t sbud = (ws_size > (size_t)NFULL * sizeof(float))
                  ? ws_size - (size_t)NFULL * sizeof(float) : 0;

    run_head<2, 1>(x, x1, Wq, bq, Wk, bk, Wv, bv, qw, kw, vw, yw, scores, partial, att, sbud, 0, 1,  stream);
    run_head<4, 2>(x, x1, Wq, bq, Wk, bk, Wv, bv, qw, kw, vw, yw, scores, partial, att, sbud, 1, 1,  stream);
    run_head<8, 3>(x, x1, Wq, bq, Wk, bk, Wv, bv, qw, kw, vw, yw, scores, partial, att, sbud, 2, 8,  stream);
    run_head<16,4>(x, x1, Wq, bq, Wk, bk, Wv, bv, qw, kw, vw, yw, scores, partial, att, sbud, 3, 64, stream);

    conv_kernel<<<dim3(96, 4, BT), dim3(256), 0, stream>>>(att, Wo, bo, convout);
    hipMemcpyAsync(out, convout, (size_t)NFULL * sizeof(float), hipMemcpyDeviceToDevice, stream);
}

// Round 3
// 3648.174 us; speedup vs baseline: 2.0540x; 2.0540x over previous
//
#include <hip/hip_runtime.h>
#include <math.h>

#define BT 16
#define CCH 256
#define IH 96
#define IW 96
#define HW (IH*IW)            // 9216
#define DK 64

static const long long WIN   = (long long)BT * HW * DK;   // 9,437,184 floats (one head, all bt)
static const long long NFULL = 4 * WIN;                    // 37,748,736 floats

typedef __attribute__((ext_vector_type(8))) short bf16x8;
typedef __attribute__((ext_vector_type(4))) float f32x4;

__device__ __forceinline__ float bf2f(unsigned short u) {
    unsigned int x = ((unsigned int)u) << 16;
    return __uint_as_float(x);
}
__device__ __forceinline__ unsigned short f2bf(float f) {
    unsigned int x = __float_as_uint(f);
    unsigned int r = (x + 0x7FFFu + ((x >> 16) & 1u)) >> 16;
    return (unsigned short)r;
}

// ---------------- fused 1x1-conv projection + window layout
template<int P, int LOGP>
__global__ __launch_bounds__(256) void proj_win_kernel(const float* __restrict__ x,
        const float* __restrict__ W, const float* __restrict__ bias,
        float* __restrict__ out, int head)
{
    constexpr int SIDE = 96 / P;
    constexpr int NWIN = SIDE * SIDE;
    constexpr int DLEN = DK * P * P;
    constexpr int PP = P * P;
    __shared__ float Xs[16][128];
    __shared__ float Wsh[64][16];
    int tid = threadIdx.x;
    int g0 = blockIdx.x * 128;
    int bt = blockIdx.z;
    int o0 = head * DK;
    int sc = tid & 31, orow = tid >> 5;

    int rowslot[2], spix0[2];
    #pragma unroll
    for (int l = 0; l < 2; l++) {
        int flat = l * 1024 + tid * 4;
        int row = flat >> 7, p4 = flat & 127;
        rowslot[l] = row;
        int g = g0 + p4;
        int n = g >> (2 * LOGP);
        int pyx = g & (PP - 1);
        int py = pyx >> LOGP, px = pyx & (P - 1);
        int oh = n / SIDE, ow = n - oh * SIDE;
        spix0[l] = (oh * P + py) * IW + ow * P + px;
    }

    float acc[8][4] = {};
    const float* xb = x + (long long)bt * CCH * HW;
    for (int kc = 0; kc < CCH; kc += 16) {
        #pragma unroll
        for (int l = 0; l < 2; l++) {
            const float* src = xb + (long long)(kc + rowslot[l]) * HW + spix0[l];
            int p4 = (l * 1024 + tid * 4) & 127;
            if constexpr (P == 2) {
                float2 a = *(const float2*)(src);
                float2 b = *(const float2*)(src + IW);
                Xs[rowslot[l]][p4 + 0] = a.x; Xs[rowslot[l]][p4 + 1] = a.y;
                Xs[rowslot[l]][p4 + 2] = b.x; Xs[rowslot[l]][p4 + 3] = b.y;
            } else {
                float4 v = *(const float4*)(src);
                *(float4*)(&Xs[rowslot[l]][p4]) = v;
            }
        }
        {
            int row = tid >> 2, c4 = (tid & 3) * 4;
            float4 wv = *(const float4*)(W + (long long)(o0 + row) * CCH + kc + c4);
            *(float4*)(&Wsh[row][c4]) = wv;
        }
        __syncthreads();
        #pragma unroll
        for (int kk = 0; kk < 16; kk++) {
            float4 xv = *(const float4*)(&Xs[kk][sc * 4]);
            #pragma unroll
            for (int r = 0; r < 8; r++) {
                float wv = Wsh[orow * 8 + r][kk];
                acc[r][0] += wv * xv.x; acc[r][1] += wv * xv.y;
                acc[r][2] += wv * xv.z; acc[r][3] += wv * xv.w;
            }
        }
        __syncthreads();
    }
    int g = g0 + sc * 4;
    int n = g >> (2 * LOGP);
    int pyx = g & (PP - 1);
    long long base = ((long long)bt * NWIN + n) * DLEN + pyx;
    #pragma unroll
    for (int r = 0; r < 8; r++) {
        int ch = orow * 8 + r;
        float bv = bias[o0 + ch];
        float4 res;
        res.x = acc[r][0] + bv; res.y = acc[r][1] + bv;
        res.z = acc[r][2] + bv; res.w = acc[r][3] + bv;
        *(float4*)(&out[base + (long long)ch * PP]) = res;
    }
}

// ---------------- QK^T 64x64 tile (optional split-K)
__global__ __launch_bounds__(256) void qk_kernel(const float* __restrict__ qw,
    const float* __restrict__ kw, float* __restrict__ scores,
    float* __restrict__ partial, int nw, int dlen, float scale, int ksplit,
    int tspan, int bt0)
{
    __shared__ float Qs[64][20];
    __shared__ float Ks[64][20];
    int tid = threadIdx.x;
    int m0 = blockIdx.x * 64;
    int n0 = blockIdx.y * 64;
    int btl = blockIdx.z / ksplit;
    int kidx = blockIdx.z - btl * ksplit;
    int bt = bt0 + btl;
    int dchunk = dlen / ksplit;
    long long kbase = (long long)kidx * dchunk;
    int tx = tid & 15, ty = tid >> 4;
    float acc[4][4] = {};
    const float* qb = qw + (long long)bt * nw * dlen;
    const float* kb = kw + (long long)bt * nw * dlen;
    int lr = tid >> 2, lc = (tid & 3) * 4;
    for (int kc = 0; kc < dchunk; kc += 16) {
        float4 qv = make_float4(0.f, 0.f, 0.f, 0.f);
        if (n0 + lr < nw) qv = *(const float4*)(qb + (long long)(n0 + lr) * dlen + kbase + kc + lc);
        float4 kv = make_float4(0.f, 0.f, 0.f, 0.f);
        if (m0 + lr < nw) kv = *(const float4*)(kb + (long long)(m0 + lr) * dlen + kbase + kc + lc);
        *(float4*)(&Qs[lr][lc]) = qv;
        *(float4*)(&Ks[lr][lc]) = kv;
        __syncthreads();
        #pragma unroll
        for (int kk = 0; kk < 16; kk++) {
            float a0 = Qs[ty*4+0][kk], a1 = Qs[ty*4+1][kk];
            float a2 = Qs[ty*4+2][kk], a3 = Qs[ty*4+3][kk];
            float b0 = Ks[tx+ 0][kk], b1 = Ks[tx+16][kk];
            float b2 = Ks[tx+32][kk], b3 = Ks[tx+48][kk];
            acc[0][0] += a0*b0; acc[0][1] += a0*b1; acc[0][2] += a0*b2; acc[0][3] += a0*b3;
            acc[1][0] += a1*b0; acc[1][1] += a1*b1; acc[1][2] += a1*b2; acc[1][3] += a1*b3;
            acc[2][0] += a2*b0; acc[2][1] += a2*b1; acc[2][2] += a2*b2; acc[2][3] += a2*b3;
            acc[3][0] += a3*b0; acc[3][1] += a3*b1; acc[3][2] += a3*b2; acc[3][3] += a3*b3;
        }
        __syncthreads();
    }
    if (ksplit == 1) {
        #pragma unroll
        for (int i = 0; i < 4; i++) {
            int r = n0 + ty * 4 + i;
            if (r >= nw) continue;
            #pragma unroll
            for (int j = 0; j < 4; j++) {
                int c = m0 + tx + 16 * j;
                if (c < nw)
                    scores[((long long)btl * nw + r) * nw + c] = acc[i][j] * scale;
            }
        }
    } else {
        #pragma unroll
        for (int i = 0; i < 4; i++)
            #pragma unroll
            for (int j = 0; j < 4; j++)
                partial[(((long long)btl * ksplit + kidx) * tspan + (n0 + ty*4 + i)) * tspan + (m0 + tx + 16*j)] = acc[i][j];
    }
}

__global__ __launch_bounds__(256) void qk_reduce_kernel(const float* __restrict__ partial,
    float* __restrict__ scores, int nw, int tspan, int ksplit, float scale, int btc)
{
    long long idx = (long long)blockIdx.x * 256 + threadIdx.x;
    if (idx >= (long long)btc * nw * nw) return;
    int m = (int)(idx % nw);
    long long t = idx / nw;
    int n = (int)(t % nw);
    int btl = (int)(t / nw);
    float s = 0.f;
    for (int k = 0; k < ksplit; k++)
        s += partial[(((long long)btl * ksplit + k) * tspan + n) * tspan + m];
    scores[((long long)btl * nw + n) * nw + m] = s * scale;
}

// ---------------- row softmax (fp32 scores in-place)
__global__ __launch_bounds__(256) void softmax_kernel(float* __restrict__ scores, int nw)
{
    __shared__ float red[8];
    int n = blockIdx.x, btl = blockIdx.y;
    float* row = scores + ((long long)btl * nw + n) * nw;
    int tid = threadIdx.x;
    float vals[9];
    float lmax = -3e38f;
    #pragma unroll
    for (int it = 0; it < 9; it++) {
        int m = tid + it * 256;
        if (m < nw) { vals[it] = row[m]; lmax = fmaxf(lmax, vals[it]); }
        else vals[it] = -3e38f;
    }
    #pragma unroll
    for (int o = 32; o > 0; o >>= 1) lmax = fmaxf(lmax, __shfl_down(lmax, o, 64));
    if ((tid & 63) == 0) red[tid >> 6] = lmax;
    __syncthreads();
    float rmax = fmaxf(fmaxf(red[0], red[1]), fmaxf(red[2], red[3]));
    __syncthreads();
    float lsum = 0.f;
    #pragma unroll
    for (int it = 0; it < 9; it++) {
        int m = tid + it * 256;
        if (m < nw) { vals[it] = __expf(vals[it] - rmax); lsum += vals[it]; }
    }
    #pragma unroll
    for (int o = 32; o > 0; o >>= 1) lsum += __shfl_down(lsum, o, 64);
    if ((tid & 63) == 0) red[tid >> 6] = lsum;
    __syncthreads();
    float rsum = red[0] + red[1] + red[2] + red[3];
    float inv = 1.f / rsum;
    #pragma unroll
    for (int it = 0; it < 9; it++) {
        int m = tid + it * 256;
        if (m < nw) row[m] = vals[it] * inv;
    }
}

// ---------------- P @ V  64(n) x 64(d) tile
__global__ __launch_bounds__(256) void pv_kernel(const float* __restrict__ p,
    const float* __restrict__ vw, float* __restrict__ yw, int nw, int dlen, int bt0)
{
    __shared__ float Ps[64][20];
    __shared__ float Vs[16][68];
    int tid = threadIdx.x;
    int d0 = blockIdx.x * 64;
    int n0 = blockIdx.y * 64;
    int btl = blockIdx.z;
    int bt = bt0 + btl;
    int tx = tid & 15, ty = tid >> 4;
    float acc[4][4] = {};
    const float* pb = p + (long long)btl * nw * nw;
    const float* vb = vw + (long long)bt * nw * dlen;
    int plr = tid >> 2, plc = (tid & 3) * 4;
    int vlr = tid >> 4, vlc = (tid & 15) * 4;
    for (int mc = 0; mc < nw; mc += 16) {
        float4 pv4 = make_float4(0.f, 0.f, 0.f, 0.f);
        if (n0 + plr < nw) {
            int mbase = mc + plc;
            if (mbase + 3 < nw) {
                pv4 = *(const float4*)(pb + (long long)(n0 + plr) * nw + mbase);
            } else {
                float tmp[4] = {0.f, 0.f, 0.f, 0.f};
                for (int e = 0; e < 4; e++)
                    if (mbase + e < nw) tmp[e] = pb[(long long)(n0 + plr) * nw + mbase + e];
                pv4 = make_float4(tmp[0], tmp[1], tmp[2], tmp[3]);
            }
        }
        *(float4*)(&Ps[plr][plc]) = pv4;
        float4 vv = make_float4(0.f, 0.f, 0.f, 0.f);
        if (mc + vlr < nw) vv = *(const float4*)(vb + (long long)(mc + vlr) * dlen + d0 + vlc);
        *(float4*)(&Vs[vlr][vlc]) = vv;
        __syncthreads();
        #pragma unroll
        for (int mm = 0; mm < 16; mm++) {
            float4 bv = *(const float4*)(&Vs[mm][tx * 4]);
            float a0 = Ps[ty*4+0][mm], a1 = Ps[ty*4+1][mm];
            float a2 = Ps[ty*4+2][mm], a3 = Ps[ty*4+3][mm];
            acc[0][0] += a0*bv.x; acc[0][1] += a0*bv.y; acc[0][2] += a0*bv.z; acc[0][3] += a0*bv.w;
            acc[1][0] += a1*bv.x; acc[1][1] += a1*bv.y; acc[1][2] += a1*bv.z; acc[1][3] += a1*bv.w;
            acc[2][0] += a2*bv.x; acc[2][1] += a2*bv.y; acc[2][2] += a2*bv.z; acc[2][3] += a2*bv.w;
            acc[3][0] += a3*bv.x; acc[3][1] += a3*bv.y; acc[3][2] += a3*bv.z; acc[3][3] += a3*bv.w;
        }
        __syncthreads();
    }
    #pragma unroll
    for (int i = 0; i < 4; i++) {
        int r = n0 + ty * 4 + i;
        if (r >= nw) continue;
        float4 res;
        res.x = acc[i][0]; res.y = acc[i][1]; res.z = acc[i][2]; res.w = acc[i][3];
        *(float4*)(yw + ((long long)bt * nw + r) * dlen + d0 + tx * 4) = res;
    }
}

// ---------------- unwindow scatter back to att[bt, c, h, w] (att == d_out)
template<int P>
__global__ __launch_bounds__(256) void unwindow_kernel(const float* __restrict__ yw,
    float* __restrict__ att, int head)
{
    constexpr int SIDE = 96 / P;
    constexpr int DLEN = DK * P * P;
    long long idx = (long long)blockIdx.x * 256 + threadIdx.x;
    if (idx >= (long long)BT * DK * HW) return;
    int x = (int)(idx % IW);
    long long t = idx / IW;
    int y = (int)(t % IH); t /= IH;
    int ch = (int)(t % DK);
    int bt = (int)(t / DK);
    int oh = y / P, py = y & (P - 1), ow = x / P, px = x & (P - 1);
    int n = oh * SIDE + ow;
    int dd = (ch * P + py) * P + px;
    att[(((long long)(bt * CCH + head * DK + ch)) * IH + y) * IW + x] =
        yw[((long long)bt * (SIDE * SIDE) + n) * DLEN + dd];
}

// ---------------- att fp32 (d_out) -> bf16 copy
__global__ __launch_bounds__(256) void to_bf16_kernel(const float* __restrict__ in,
    unsigned short* __restrict__ outb, long long n4)
{
    long long stride = (long long)gridDim.x * 256;
    for (long long i = blockIdx.x * 256LL + threadIdx.x; i < n4; i += stride) {
        float4 v = *(const float4*)(in + i * 4);
        ushort4 r;
        r.x = f2bf(v.x); r.y = f2bf(v.y); r.z = f2bf(v.z); r.w = f2bf(v.w);
        *(ushort4*)(outb + i * 4) = r;
    }
}

// ---------------- Wo fp32 [o][c][3][3] -> bf16 Wt[t][cc][o][cl]  (cc: 8 chunks of 32 ch)
__global__ __launch_bounds__(256) void transform_w_kernel(const float* __restrict__ Wo,
    unsigned short* __restrict__ Wt)
{
    int idx = blockIdx.x * 256 + threadIdx.x;
    if (idx >= 9 * 8 * 256 * 32) return;
    int cl = idx & 31;
    int o  = (idx >> 5) & 255;
    int cc = (idx >> 13) & 7;
    int t  = idx >> 16;
    int dy = t / 3, dx = t - dy * 3;
    int c = cc * 32 + cl;
    Wt[idx] = f2bf(Wo[((long long)(o * CCH + c) * 3 + dy) * 3 + dx]);
}

// ---------------- 3x3 conv via bf16 MFMA implicit GEMM + bias + LeakyReLU
// block: 64 out-ch x (4 rows x 96 px); wave w owns row w. grid (24, 4, 16).
__global__ __launch_bounds__(256) void conv_mfma_kernel(
    const unsigned short* __restrict__ att_bf, const unsigned short* __restrict__ Wt,
    const float* __restrict__ bo, float* __restrict__ out)
{
    __shared__ unsigned short in_t[6 * 104 * 32];   // [row][px][ch32], px-swizzled
    int tid = threadIdx.x;
    int ytile = blockIdx.x, otile = blockIdx.y, bt = blockIdx.z;
    int ybase = ytile * 4, o0 = otile * 64;
    int w = tid >> 6, l = tid & 63;
    int l15 = l & 15, lg = l >> 4;

    f32x4 acc[4][6];
    #pragma unroll
    for (int mf = 0; mf < 4; mf++)
        #pragma unroll
        for (int nf = 0; nf < 6; nf++)
            acc[mf][nf] = (f32x4){0.f, 0.f, 0.f, 0.f};

    // zero the two halo columns (px 0 and 97) once
    for (int it = tid; it < 96; it += 256) {
        int side = it / 48, rem = it - side * 48;
        int row = rem >> 3, cg = rem & 7;
        int px = side ? 97 : 0;
        int byte = (((row * 104 + px) * 64) + cg * 8) ^ ((px & 3) << 4);
        ushort4 z = {0, 0, 0, 0};
        *(ushort4*)((char*)in_t + byte) = z;
    }

    const unsigned short* ab = att_bf + (long long)bt * CCH * HW;

    for (int cc = 0; cc < 8; cc++) {
        __syncthreads();
        // stage 32 ch x 6 rows x 96 px, transposed + swizzled
        for (int it = tid; it < 1152; it += 256) {
            int x4 = it % 24;
            int cg = (it / 24) & 7;
            int row = it / 192;
            int ya = ybase + row - 1;
            ushort4 v0, v1, v2, v3;
            if (ya >= 0 && ya < IH) {
                const unsigned short* p = ab + (long long)(cc * 32 + cg * 4) * HW + ya * IW + x4 * 4;
                v0 = *(const ushort4*)(p);
                v1 = *(const ushort4*)(p + HW);
                v2 = *(const ushort4*)(p + 2 * HW);
                v3 = *(const ushort4*)(p + 3 * HW);
            } else {
                v0 = v1 = v2 = v3 = (ushort4){0, 0, 0, 0};
            }
            int pxb = x4 * 4 + 1;
            int rowoff = row * 104;
            ushort4 t0 = {v0.x, v1.x, v2.x, v3.x};
            ushort4 t1 = {v0.y, v1.y, v2.y, v3.y};
            ushort4 t2 = {v0.z, v1.z, v2.z, v3.z};
            ushort4 t3 = {v0.w, v1.w, v2.w, v3.w};
            int b0 = (((rowoff + pxb + 0) * 64) + cg * 8) ^ (((pxb + 0) & 3) << 4);
            int b1 = (((rowoff + pxb + 1) * 64) + cg * 8) ^ (((pxb + 1) & 3) << 4);
            int b2 = (((rowoff + pxb + 2) * 64) + cg * 8) ^ (((pxb + 2) & 3) << 4);
            int b3 = (((rowoff + pxb + 3) * 64) + cg * 8) ^ (((pxb + 3) & 3) << 4);
            *(ushort4*)((char*)in_t + b0) = t0;
            *(ushort4*)((char*)in_t + b1) = t1;
            *(ushort4*)((char*)in_t + b2) = t2;
            *(ushort4*)((char*)in_t + b3) = t3;
        }
        __syncthreads();

        for (int t = 0; t < 9; t++) {
            int dy = t / 3, dx = t - dy * 3;
            bf16x8 a[4];
            const unsigned short* wp = Wt + ((long long)(t * 8 + cc) * 256 + o0) * 32 + lg * 8;
            #pragma unroll
            for (int mf = 0; mf < 4; mf++)
                a[mf] = *(const bf16x8*)(wp + (mf * 16 + l15) * 32);
            int rowoff = (w + dy) * 104;
            #pragma unroll
            for (int nf = 0; nf < 6; nf++) {
                int px = nf * 16 + l15 + dx;
                int byte = (((rowoff + px) * 64) + lg * 16) ^ ((px & 3) << 4);
                bf16x8 b = *(const bf16x8*)((const char*)in_t + byte);
                #pragma unroll
                for (int mf = 0; mf < 4; mf++)
                    acc[mf][nf] = __builtin_amdgcn_mfma_f32_16x16x32_bf16(a[mf], b, acc[mf][nf], 0, 0, 0);
            }
        }
    }

    // epilogue: bias + LeakyReLU, C/D layout col=lane&15 (px), row=(lane>>4)*4+reg (o)
    int y = ybase + w;
    #pragma unroll
    for (int mf = 0; mf < 4; mf++) {
        #pragma unroll
        for (int reg = 0; reg < 4; reg++) {
            int o = o0 + mf * 16 + lg * 4 + reg;
            float bv = bo[o];
            long long obase = (((long long)bt * CCH + o) * IH + y) * IW;
            #pragma unroll
            for (int nf = 0; nf < 6; nf++) {
                int x = nf * 16 + l15;
                float v = acc[mf][nf][reg] + bv;
                out[obase + x] = v >= 0.f ? v : 0.2f * v;
            }
        }
    }
}

// ---------------- per-head host driver
template<int P, int LOGP>
static void run_head(const float* x, const float* x1,
                     const float* Wq, const float* bq,
                     const float* Wk, const float* bk,
                     const float* Wv, const float* bv,
                     float* qw, float* kw, float* vw, float* yw,
                     float* scores, float* partial, float* att,
                     size_t sbud, int head, int ks, hipStream_t stream)
{
    constexpr int SIDE = 96 / P;
    constexpr int NWIN = SIDE * SIDE;
    constexpr int DLEN = DK * P * P;
    int nw = NWIN, dlen = DLEN;
    float scale = 1.0f / sqrtf((float)dlen);
    int nt = (nw + 63) / 64;
    int tspan = nt * 64;
    dim3 blk(256);

    proj_win_kernel<P, LOGP><<<dim3(72, 1, BT), blk, 0, stream>>>(x,  Wq, bq, qw, head);
    proj_win_kernel<P, LOGP><<<dim3(72, 1, BT), blk, 0, stream>>>(x1, Wk, bk, kw, head);
    proj_win_kernel<P, LOGP><<<dim3(72, 1, BT), blk, 0, stream>>>(x1, Wv, bv, vw, head);

    int btc = BT;
    while (btc > 1 && (size_t)btc * nw * nw * sizeof(float) > sbud) btc >>= 1;

    for (int bt0 = 0; bt0 < BT; bt0 += btc) {
        qk_kernel<<<dim3(nt, nt, btc * ks), blk, 0, stream>>>(qw, kw, scores, partial,
                                                              nw, dlen, scale, ks, tspan, bt0);
        if (ks > 1) {
            long long tot = (long long)btc * nw * nw;
            qk_reduce_kernel<<<(unsigned)((tot + 255) / 256), blk, 0, stream>>>(
                partial, scores, nw, tspan, ks, scale, btc);
        }
        softmax_kernel<<<dim3(nw, btc), blk, 0, stream>>>(scores, nw);
        pv_kernel<<<dim3(dlen / 64, nt, btc), blk, 0, stream>>>(scores, vw, yw, nw, dlen, bt0);
    }
    unwindow_kernel<P><<<36864, blk, 0, stream>>>(yw, att, head);
}

extern "C" void kernel_launch(void* const* d_in, const int* in_sizes, int n_in,
                              void* d_out, int out_size, void* d_ws, size_t ws_size,
                              hipStream_t stream) {
    const float* x  = (const float*)d_in[0];
    const float* x1 = (const float*)d_in[1];
    const float* Wq = (const float*)d_in[2];
    const float* bq = (const float*)d_in[3];
    const float* Wk = (const float*)d_in[4];
    const float* bk = (const float*)d_in[5];
    const float* Wv = (const float*)d_in[6];
    const float* bv = (const float*)d_in[7];
    const float* Wo = (const float*)d_in[8];
    const float* bo = (const float*)d_in[9];
    float* out = (float*)d_out;

    float* ws = (float*)d_ws;
    float* qw = ws;                 // WIN
    float* kw = ws + WIN;           // WIN
    float* vw = ws + 2 * WIN;       // WIN
    float* yw = ws + 3 * WIN;       // WIN (also split-K partial)
    float* scores  = ws + NFULL;    // adaptive size
    float* partial = yw;
    float* att = out;               // attention output staged in d_out (fp32)

    // conv-phase overlays (regions dead after last head):
    unsigned short* att_bf = (unsigned short*)ws;            // NFULL bf16 = qw+kw region
    unsigned short* Wt     = (unsigned short*)(ws + 2 * WIN); // 589824 bf16 in vw region

    size_t sbud = (ws_size > (size_t)NFULL * sizeof(float))
                  ? ws_size - (size_t)NFULL * sizeof(float) : 0;

    run_head<2, 1>(x, x1, Wq, bq, Wk, bk, Wv, bv, qw, kw, vw, yw, scores, partial, att, sbud, 0, 1,  stream);
    run_head<4, 2>(x, x1, Wq, bq, Wk, bk, Wv, bv, qw, kw, vw, yw, scores, partial, att, sbud, 1, 1,  stream);
    run_head<8, 3>(x, x1, Wq, bq, Wk, bk, Wv, bv, qw, kw, vw, yw, scores, partial, att, sbud, 2, 8,  stream);
    run_head<16,4>(x, x1, Wq, bq, Wk, bk, Wv, bv, qw, kw, vw, yw, scores, partial, att, sbud, 3, 64, stream);

    transform_w_kernel<<<(9 * 8 * 256 * 32 + 255) / 256, dim3(256), 0, stream>>>(Wo, Wt);
    to_bf16_kernel<<<2048, dim3(256), 0, stream>>>(att, att_bf, NFULL / 4);
    conv_mfma_kernel<<<dim3(24, 4, BT), dim3(256), 0, stream>>>(att_bf, Wt, bo, out);
}

// Round 4
// 2083.694 us; speedup vs baseline: 3.5961x; 1.7508x over previous
//
#include <hip/hip_runtime.h>
#include <math.h>

#define BT 16
#define CCH 256
#define IH 96
#define IW 96
#define HW (IH*IW)            // 9216
#define DK 64

static const long long WIN   = (long long)BT * HW * DK;   // 9,437,184 elems (one head, all bt)
static const long long NFULL = 4 * WIN;                    // 37,748,736 elems
static const long long WB    = WIN * 2;                    // bytes of one bf16 head buffer

typedef __attribute__((ext_vector_type(8))) short bf16x8;
typedef __attribute__((ext_vector_type(4))) float f32x4;

__device__ __forceinline__ float bf2f(unsigned short u) {
    unsigned int x = ((unsigned int)u) << 16;
    return __uint_as_float(x);
}
__device__ __forceinline__ unsigned short f2bf(float f) {
    unsigned int x = __float_as_uint(f);
    unsigned int r = (x + 0x7FFFu + ((x >> 16) & 1u)) >> 16;
    return (unsigned short)r;
}

// ---------------- fused 1x1-conv projection + window layout, bf16 output
template<int P, int LOGP>
__global__ __launch_bounds__(256) void proj_win_kernel(const float* __restrict__ x,
        const float* __restrict__ W, const float* __restrict__ bias,
        unsigned short* __restrict__ out, int head)
{
    constexpr int SIDE = 96 / P;
    constexpr int NWIN = SIDE * SIDE;
    constexpr int DLEN = DK * P * P;
    constexpr int PP = P * P;
    __shared__ float Xs[16][128];
    __shared__ float Wsh[64][16];
    int tid = threadIdx.x;
    int g0 = blockIdx.x * 128;
    int bt = blockIdx.z;
    int o0 = head * DK;
    int sc = tid & 31, orow = tid >> 5;

    int rowslot[2], spix0[2];
    #pragma unroll
    for (int l = 0; l < 2; l++) {
        int flat = l * 1024 + tid * 4;
        int row = flat >> 7, p4 = flat & 127;
        rowslot[l] = row;
        int g = g0 + p4;
        int n = g >> (2 * LOGP);
        int pyx = g & (PP - 1);
        int py = pyx >> LOGP, px = pyx & (P - 1);
        int oh = n / SIDE, ow = n - oh * SIDE;
        spix0[l] = (oh * P + py) * IW + ow * P + px;
    }

    float acc[8][4] = {};
    const float* xb = x + (long long)bt * CCH * HW;
    for (int kc = 0; kc < CCH; kc += 16) {
        #pragma unroll
        for (int l = 0; l < 2; l++) {
            const float* src = xb + (long long)(kc + rowslot[l]) * HW + spix0[l];
            int p4 = (l * 1024 + tid * 4) & 127;
            if constexpr (P == 2) {
                float2 a = *(const float2*)(src);
                float2 b = *(const float2*)(src + IW);
                Xs[rowslot[l]][p4 + 0] = a.x; Xs[rowslot[l]][p4 + 1] = a.y;
                Xs[rowslot[l]][p4 + 2] = b.x; Xs[rowslot[l]][p4 + 3] = b.y;
            } else {
                float4 v = *(const float4*)(src);
                *(float4*)(&Xs[rowslot[l]][p4]) = v;
            }
        }
        {
            int row = tid >> 2, c4 = (tid & 3) * 4;
            float4 wv = *(const float4*)(W + (long long)(o0 + row) * CCH + kc + c4);
            *(float4*)(&Wsh[row][c4]) = wv;
        }
        __syncthreads();
        #pragma unroll
        for (int kk = 0; kk < 16; kk++) {
            float4 xv = *(const float4*)(&Xs[kk][sc * 4]);
            #pragma unroll
            for (int r = 0; r < 8; r++) {
                float wv = Wsh[orow * 8 + r][kk];
                acc[r][0] += wv * xv.x; acc[r][1] += wv * xv.y;
                acc[r][2] += wv * xv.z; acc[r][3] += wv * xv.w;
            }
        }
        __syncthreads();
    }
    int g = g0 + sc * 4;
    int n = g >> (2 * LOGP);
    int pyx = g & (PP - 1);
    long long base = ((long long)bt * NWIN + n) * DLEN + pyx;
    #pragma unroll
    for (int r = 0; r < 8; r++) {
        int ch = orow * 8 + r;
        float bv = bias[o0 + ch];
        ushort4 res;
        res.x = f2bf(acc[r][0] + bv); res.y = f2bf(acc[r][1] + bv);
        res.z = f2bf(acc[r][2] + bv); res.w = f2bf(acc[r][3] + bv);
        *(ushort4*)(&out[base + (long long)ch * PP]) = res;
    }
}

// ---------------- QK^T via bf16 MFMA, 64x64 tile, optional split-K
__global__ __launch_bounds__(256) void qk_mfma_kernel(const unsigned short* __restrict__ qw,
    const unsigned short* __restrict__ kw, float* __restrict__ scores,
    float* __restrict__ partial, int nw, int dlen, float scale, int ksplit,
    int tspan, int bt0)
{
    __shared__ alignas(16) unsigned short Qs[64 * 64];
    __shared__ alignas(16) unsigned short Ks[64 * 64];
    int tid = threadIdx.x;
    int m0 = blockIdx.x * 64, n0 = blockIdx.y * 64;
    int btl = blockIdx.z / ksplit;
    int kidx = blockIdx.z - btl * ksplit;
    int bt = bt0 + btl;
    int dchunk = dlen / ksplit;
    long long kbase = (long long)kidx * dchunk;
    int w = tid >> 6, l = tid & 63, l15 = l & 15, lg = l >> 4;
    f32x4 acc[4];
    #pragma unroll
    for (int nf = 0; nf < 4; nf++) acc[nf] = (f32x4){0.f, 0.f, 0.f, 0.f};

    const unsigned short* qb = qw + ((long long)bt * nw + n0) * dlen + kbase;
    const unsigned short* kb = kw + ((long long)bt * nw + m0) * dlen + kbase;
    int qrows = nw - n0; if (qrows > 64) qrows = 64;
    int krows = nw - m0; if (krows > 64) krows = 64;
    int arow = w * 16 + l15;
    int aswz = arow * 64 + 0;

    for (int kc = 0; kc < dchunk; kc += 64) {
        if (kc) __syncthreads();
        #pragma unroll
        for (int i = 0; i < 2; i++) {
            int c = tid + i * 256;
            int row = c >> 3, kg = c & 7;
            int kgs = (kg ^ (row & 7)) * 8;
            bf16x8 qv = {0,0,0,0,0,0,0,0};
            bf16x8 kv = {0,0,0,0,0,0,0,0};
            if (row < qrows) qv = *(const bf16x8*)(qb + (long long)row * dlen + kc + kg * 8);
            if (row < krows) kv = *(const bf16x8*)(kb + (long long)row * dlen + kc + kg * 8);
            *(bf16x8*)(Qs + row * 64 + kgs) = qv;
            *(bf16x8*)(Ks + row * 64 + kgs) = kv;
        }
        __syncthreads();
        #pragma unroll
        for (int k0 = 0; k0 < 64; k0 += 32) {
            int kg = (k0 >> 3) + lg;
            bf16x8 a = *(const bf16x8*)(Qs + arow * 64 + (kg ^ (arow & 7)) * 8);
            #pragma unroll
            for (int nf = 0; nf < 4; nf++) {
                int col = nf * 16 + l15;
                bf16x8 b = *(const bf16x8*)(Ks + col * 64 + (kg ^ (col & 7)) * 8);
                acc[nf] = __builtin_amdgcn_mfma_f32_16x16x32_bf16(a, b, acc[nf], 0, 0, 0);
            }
        }
    }

    if (ksplit == 1) {
        #pragma unroll
        for (int nf = 0; nf < 4; nf++) {
            int c = m0 + nf * 16 + l15;
            #pragma unroll
            for (int reg = 0; reg < 4; reg++) {
                int r = n0 + w * 16 + lg * 4 + reg;
                if (r < nw && c < nw)
                    scores[((long long)btl * nw + r) * nw + c] = acc[nf][reg] * scale;
            }
        }
    } else {
        #pragma unroll
        for (int nf = 0; nf < 4; nf++) {
            int c = m0 + nf * 16 + l15;
            #pragma unroll
            for (int reg = 0; reg < 4; reg++) {
                int r = n0 + w * 16 + lg * 4 + reg;
                partial[(((long long)btl * ksplit + kidx) * tspan + r) * tspan + c] = acc[nf][reg];
            }
        }
    }
}

__global__ __launch_bounds__(256) void qk_reduce_kernel(const float* __restrict__ partial,
    float* __restrict__ scores, int nw, int tspan, int ksplit, float scale, int btc)
{
    long long idx = (long long)blockIdx.x * 256 + threadIdx.x;
    if (idx >= (long long)btc * nw * nw) return;
    int m = (int)(idx % nw);
    long long t = idx / nw;
    int n = (int)(t % nw);
    int btl = (int)(t / nw);
    float s = 0.f;
    for (int k = 0; k < ksplit; k++)
        s += partial[(((long long)btl * ksplit + k) * tspan + n) * tspan + m];
    scores[((long long)btl * nw + n) * nw + m] = s * scale;
}

// ---------------- row softmax: fp32 scores in, bf16 P out
__global__ __launch_bounds__(256) void softmax_kernel(const float* __restrict__ scores,
    unsigned short* __restrict__ pb16, int nw)
{
    __shared__ float red[8];
    int n = blockIdx.x, btl = blockIdx.y;
    const float* row = scores + ((long long)btl * nw + n) * nw;
    unsigned short* prow = pb16 + ((long long)btl * nw + n) * nw;
    int tid = threadIdx.x;
    float vals[9];
    float lmax = -3e38f;
    #pragma unroll
    for (int it = 0; it < 9; it++) {
        int m = tid + it * 256;
        if (m < nw) { vals[it] = row[m]; lmax = fmaxf(lmax, vals[it]); }
        else vals[it] = -3e38f;
    }
    #pragma unroll
    for (int o = 32; o > 0; o >>= 1) lmax = fmaxf(lmax, __shfl_down(lmax, o, 64));
    if ((tid & 63) == 0) red[tid >> 6] = lmax;
    __syncthreads();
    float rmax = fmaxf(fmaxf(red[0], red[1]), fmaxf(red[2], red[3]));
    __syncthreads();
    float lsum = 0.f;
    #pragma unroll
    for (int it = 0; it < 9; it++) {
        int m = tid + it * 256;
        if (m < nw) { vals[it] = __expf(vals[it] - rmax); lsum += vals[it]; }
    }
    #pragma unroll
    for (int o = 32; o > 0; o >>= 1) lsum += __shfl_down(lsum, o, 64);
    if ((tid & 63) == 0) red[tid >> 6] = lsum;
    __syncthreads();
    float rsum = red[0] + red[1] + red[2] + red[3];
    float inv = 1.f / rsum;
    #pragma unroll
    for (int it = 0; it < 9; it++) {
        int m = tid + it * 256;
        if (m < nw) prow[m] = f2bf(vals[it] * inv);
    }
}

// ---------------- P @ V via bf16 MFMA; 64(n) x 64(d) tile, V transpose-staged
__global__ __launch_bounds__(256) void pv_mfma_kernel(const unsigned short* __restrict__ p,
    const unsigned short* __restrict__ vw, float* __restrict__ yw, int nw, int dlen, int bt0)
{
    __shared__ alignas(16) unsigned short Ps[64 * 64];
    __shared__ alignas(16) unsigned short Vt[64 * 64];
    int tid = threadIdx.x;
    int d0 = blockIdx.x * 64, n0 = blockIdx.y * 64;
    int btl = blockIdx.z;
    int bt = bt0 + btl;
    int w = tid >> 6, l = tid & 63, l15 = l & 15, lg = l >> 4;
    f32x4 acc[4];
    #pragma unroll
    for (int nf = 0; nf < 4; nf++) acc[nf] = (f32x4){0.f, 0.f, 0.f, 0.f};

    const unsigned short* pb = p + ((long long)btl * nw + n0) * nw;
    const unsigned short* vb = vw + (long long)bt * nw * dlen + d0;
    int prows = nw - n0; if (prows > 64) prows = 64;
    int arow = w * 16 + l15;
    int du = tid & 15, mu = tid >> 4;

    for (int mc = 0; mc < nw; mc += 64) {
        if (mc) __syncthreads();
        int mrem = nw - mc;
        // stage P tile [n][m]
        #pragma unroll
        for (int i = 0; i < 2; i++) {
            int c = tid + i * 256;
            int row = c >> 3, kg = c & 7;
            bf16x8 v = {0,0,0,0,0,0,0,0};
            if (row < prows) {
                int mb = kg * 8;
                if (mb + 8 <= mrem) v = *(const bf16x8*)(pb + (long long)row * nw + mc + mb);
                else if (mb < mrem) {
                    for (int e = 0; e < mrem - mb; e++)
                        v[e] = (short)pb[(long long)row * nw + mc + mb + e];
                }
            }
            *(bf16x8*)(Ps + row * 64 + (kg ^ (row & 7)) * 8) = v;
        }
        // stage V^T tile [d][m] (transpose 4m x 4d units)
        {
            ushort4 vv[4];
            #pragma unroll
            for (int i = 0; i < 4; i++) {
                int m = mc + mu * 4 + i;
                if (m < nw) vv[i] = *(const ushort4*)(vb + (long long)m * dlen + du * 4);
                else vv[i] = (ushort4){0, 0, 0, 0};
            }
            #pragma unroll
            for (int j = 0; j < 4; j++) {
                int d = du * 4 + j;
                int byte = d * 128 + (((mu >> 1) ^ (d & 7)) * 16) + (mu & 1) * 8;
                ushort4 tj;
                tj.x = ((const unsigned short*)&vv[0])[j];
                tj.y = ((const unsigned short*)&vv[1])[j];
                tj.z = ((const unsigned short*)&vv[2])[j];
                tj.w = ((const unsigned short*)&vv[3])[j];
                *(ushort4*)((char*)Vt + byte) = tj;
            }
        }
        __syncthreads();
        #pragma unroll
        for (int k0 = 0; k0 < 64; k0 += 32) {
            int kg = (k0 >> 3) + lg;
            bf16x8 a = *(const bf16x8*)(Ps + arow * 64 + (kg ^ (arow & 7)) * 8);
            #pragma unroll
            for (int nf = 0; nf < 4; nf++) {
                int col = nf * 16 + l15;
                bf16x8 b = *(const bf16x8*)(Vt + col * 64 + (kg ^ (col & 7)) * 8);
                acc[nf] = __builtin_amdgcn_mfma_f32_16x16x32_bf16(a, b, acc[nf], 0, 0, 0);
            }
        }
    }

    #pragma unroll
    for (int nf = 0; nf < 4; nf++) {
        int d = d0 + nf * 16 + l15;
        #pragma unroll
        for (int reg = 0; reg < 4; reg++) {
            int n = n0 + w * 16 + lg * 4 + reg;
            if (n < nw)
                yw[((long long)bt * nw + n) * dlen + d] = acc[nf][reg];
        }
    }
}

// ---------------- unwindow scatter back to att[bt, c, h, w] (att == d_out)
template<int P>
__global__ __launch_bounds__(256) void unwindow_kernel(const float* __restrict__ yw,
    float* __restrict__ att, int head)
{
    constexpr int SIDE = 96 / P;
    constexpr int DLEN = DK * P * P;
    long long idx = (long long)blockIdx.x * 256 + threadIdx.x;
    if (idx >= (long long)BT * DK * HW) return;
    int x = (int)(idx % IW);
    long long t = idx / IW;
    int y = (int)(t % IH); t /= IH;
    int ch = (int)(t % DK);
    int bt = (int)(t / DK);
    int oh = y / P, py = y & (P - 1), ow = x / P, px = x & (P - 1);
    int n = oh * SIDE + ow;
    int dd = (ch * P + py) * P + px;
    att[(((long long)(bt * CCH + head * DK + ch)) * IH + y) * IW + x] =
        yw[((long long)bt * (SIDE * SIDE) + n) * DLEN + dd];
}

// ---------------- att fp32 (d_out) -> bf16 copy
__global__ __launch_bounds__(256) void to_bf16_kernel(const float* __restrict__ in,
    unsigned short* __restrict__ outb, long long n4)
{
    long long stride = (long long)gridDim.x * 256;
    for (long long i = blockIdx.x * 256LL + threadIdx.x; i < n4; i += stride) {
        float4 v = *(const float4*)(in + i * 4);
        ushort4 r;
        r.x = f2bf(v.x); r.y = f2bf(v.y); r.z = f2bf(v.z); r.w = f2bf(v.w);
        *(ushort4*)(outb + i * 4) = r;
    }
}

// ---------------- Wo fp32 [o][c][3][3] -> bf16 Wt[t][cc][o][cl]
__global__ __launch_bounds__(256) void transform_w_kernel(const float* __restrict__ Wo,
    unsigned short* __restrict__ Wt)
{
    int idx = blockIdx.x * 256 + threadIdx.x;
    if (idx >= 9 * 8 * 256 * 32) return;
    int cl = idx & 31;
    int o  = (idx >> 5) & 255;
    int cc = (idx >> 13) & 7;
    int t  = idx >> 16;
    int dy = t / 3, dx = t - dy * 3;
    int c = cc * 32 + cl;
    Wt[idx] = f2bf(Wo[((long long)(o * CCH + c) * 3 + dy) * 3 + dx]);
}

// ---------------- 3x3 conv via bf16 MFMA implicit GEMM + bias + LeakyReLU
__global__ __launch_bounds__(256) void conv_mfma_kernel(
    const unsigned short* __restrict__ att_bf, const unsigned short* __restrict__ Wt,
    const float* __restrict__ bo, float* __restrict__ out)
{
    __shared__ alignas(16) unsigned short in_t[6 * 104 * 32];   // [row][px][ch32], px-swizzled
    int tid = threadIdx.x;
    int ytile = blockIdx.x, otile = blockIdx.y, bt = blockIdx.z;
    int ybase = ytile * 4, o0 = otile * 64;
    int w = tid >> 6, l = tid & 63;
    int l15 = l & 15, lg = l >> 4;

    f32x4 acc[4][6];
    #pragma unroll
    for (int mf = 0; mf < 4; mf++)
        #pragma unroll
        for (int nf = 0; nf < 6; nf++)
            acc[mf][nf] = (f32x4){0.f, 0.f, 0.f, 0.f};

    for (int it = tid; it < 96; it += 256) {
        int side = it / 48, rem = it - side * 48;
        int row = rem >> 3, cg = rem & 7;
        int px = side ? 97 : 0;
        int byte = (((row * 104 + px) * 64) + cg * 8) ^ ((px & 3) << 4);
        ushort4 z = {0, 0, 0, 0};
        *(ushort4*)((char*)in_t + byte) = z;
    }

    const unsigned short* ab = att_bf + (long long)bt * CCH * HW;

    for (int cc = 0; cc < 8; cc++) {
        __syncthreads();
        for (int it = tid; it < 1152; it += 256) {
            int x4 = it % 24;
            int cg = (it / 24) & 7;
            int row = it / 192;
            int ya = ybase + row - 1;
            ushort4 v0, v1, v2, v3;
            if (ya >= 0 && ya < IH) {
                const unsigned short* p = ab + (long long)(cc * 32 + cg * 4) * HW + ya * IW + x4 * 4;
                v0 = *(const ushort4*)(p);
                v1 = *(const ushort4*)(p + HW);
                v2 = *(const ushort4*)(p + 2 * HW);
                v3 = *(const ushort4*)(p + 3 * HW);
            } else {
                v0 = v1 = v2 = v3 = (ushort4){0, 0, 0, 0};
            }
            int pxb = x4 * 4 + 1;
            int rowoff = row * 104;
            ushort4 t0 = {v0.x, v1.x, v2.x, v3.x};
            ushort4 t1 = {v0.y, v1.y, v2.y, v3.y};
            ushort4 t2 = {v0.z, v1.z, v2.z, v3.z};
            ushort4 t3 = {v0.w, v1.w, v2.w, v3.w};
            int b0 = (((rowoff + pxb + 0) * 64) + cg * 8) ^ (((pxb + 0) & 3) << 4);
            int b1 = (((rowoff + pxb + 1) * 64) + cg * 8) ^ (((pxb + 1) & 3) << 4);
            int b2 = (((rowoff + pxb + 2) * 64) + cg * 8) ^ (((pxb + 2) & 3) << 4);
            int b3 = (((rowoff + pxb + 3) * 64) + cg * 8) ^ (((pxb + 3) & 3) << 4);
            *(ushort4*)((char*)in_t + b0) = t0;
            *(ushort4*)((char*)in_t + b1) = t1;
            *(ushort4*)((char*)in_t + b2) = t2;
            *(ushort4*)((char*)in_t + b3) = t3;
        }
        __syncthreads();

        for (int t = 0; t < 9; t++) {
            int dy = t / 3, dx = t - dy * 3;
            bf16x8 a[4];
            const unsigned short* wp = Wt + ((long long)(t * 8 + cc) * 256 + o0) * 32 + lg * 8;
            #pragma unroll
            for (int mf = 0; mf < 4; mf++)
                a[mf] = *(const bf16x8*)(wp + (mf * 16 + l15) * 32);
            int rowoff = (w + dy) * 104;
            #pragma unroll
            for (int nf = 0; nf < 6; nf++) {
                int px = nf * 16 + l15 + dx;
                int byte = (((rowoff + px) * 64) + lg * 16) ^ ((px & 3) << 4);
                bf16x8 b = *(const bf16x8*)((const char*)in_t + byte);
                #pragma unroll
                for (int mf = 0; mf < 4; mf++)
                    acc[mf][nf] = __builtin_amdgcn_mfma_f32_16x16x32_bf16(a[mf], b, acc[mf][nf], 0, 0, 0);
            }
        }
    }

    int y = ybase + w;
    #pragma unroll
    for (int mf = 0; mf < 4; mf++) {
        #pragma unroll
        for (int reg = 0; reg < 4; reg++) {
            int o = o0 + mf * 16 + lg * 4 + reg;
            float bv = bo[o];
            long long obase = (((long long)bt * CCH + o) * IH + y) * IW;
            #pragma unroll
            for (int nf = 0; nf < 6; nf++) {
                int x = nf * 16 + l15;
                float v = acc[mf][nf][reg] + bv;
                out[obase + x] = v >= 0.f ? v : 0.2f * v;
            }
        }
    }
}

// ---------------- per-head host driver
template<int P, int LOGP>
static void run_head(const float* x, const float* x1,
                     const float* Wq, const float* bq,
                     const float* Wk, const float* bk,
                     const float* Wv, const float* bv,
                     unsigned short* qw, unsigned short* kw, unsigned short* vw,
                     float* yw, char* scratch, float* partial, float* att,
                     size_t sbud, int head, int ks, hipStream_t stream)
{
    constexpr int SIDE = 96 / P;
    constexpr int NWIN = SIDE * SIDE;
    constexpr int DLEN = DK * P * P;
    int nw = NWIN, dlen = DLEN;
    float scale = 1.0f / sqrtf((float)dlen);
    int nt = (nw + 63) / 64;
    int tspan = nt * 64;
    dim3 blk(256);

    proj_win_kernel<P, LOGP><<<dim3(72, 1, BT), blk, 0, stream>>>(x,  Wq, bq, qw, head);
    proj_win_kernel<P, LOGP><<<dim3(72, 1, BT), blk, 0, stream>>>(x1, Wk, bk, kw, head);
    proj_win_kernel<P, LOGP><<<dim3(72, 1, BT), blk, 0, stream>>>(x1, Wv, bv, vw, head);

    int btc = BT;
    while (btc > 1 && (size_t)btc * nw * nw * 6 > sbud) btc >>= 1;

    float* scores = (float*)scratch;
    unsigned short* pb16 = (unsigned short*)(scratch + (size_t)btc * nw * nw * 4);

    for (int bt0 = 0; bt0 < BT; bt0 += btc) {
        qk_mfma_kernel<<<dim3(nt, nt, btc * ks), blk, 0, stream>>>(qw, kw, scores, partial,
                                                                   nw, dlen, scale, ks, tspan, bt0);
        if (ks > 1) {
            long long tot = (long long)btc * nw * nw;
            qk_reduce_kernel<<<(unsigned)((tot + 255) / 256), blk, 0, stream>>>(
                partial, scores, nw, tspan, ks, scale, btc);
        }
        softmax_kernel<<<dim3(nw, btc), blk, 0, stream>>>(scores, pb16, nw);
        pv_mfma_kernel<<<dim3(dlen / 64, nt, btc), blk, 0, stream>>>(pb16, vw, yw, nw, dlen, bt0);
    }
    unwindow_kernel<P><<<36864, blk, 0, stream>>>(yw, att, head);
}

extern "C" void kernel_launch(void* const* d_in, const int* in_sizes, int n_in,
                              void* d_out, int out_size, void* d_ws, size_t ws_size,
                              hipStream_t stream) {
    const float* x  = (const float*)d_in[0];
    const float* x1 = (const float*)d_in[1];
    const float* Wq = (const float*)d_in[2];
    const float* bq = (const float*)d_in[3];
    const float* Wk = (const float*)d_in[4];
    const float* bk = (const float*)d_in[5];
    const float* Wv = (const float*)d_in[6];
    const float* bv = (const float*)d_in[7];
    const float* Wo = (const float*)d_in[8];
    const float* bo = (const float*)d_in[9];
    float* out = (float*)d_out;

    char* wsc = (char*)d_ws;
    unsigned short* qw = (unsigned short*)wsc;                // WIN bf16
    unsigned short* kw = qw + WIN;                            // WIN bf16
    unsigned short* vw = kw + WIN;                            // WIN bf16
    float* yw = (float*)(wsc + 3 * WB);                       // WIN fp32 [3WB, 5WB)
    float* partial = yw;                                      // split-K partials (dead before pv)
    char* scratch = wsc + 5 * WB;                             // scores fp32 + P bf16
    float* att = out;                                         // attention output staged in d_out

    // conv-phase overlays (all in regions dead after last head):
    unsigned short* att_bf = (unsigned short*)wsc;            // NFULL bf16 = [0, 4WB)
    unsigned short* Wt     = (unsigned short*)(wsc + 4 * WB); // 1.2 MB inside dead yw region

    size_t sbud = (ws_size > (size_t)(5 * WB)) ? ws_size - (size_t)(5 * WB) : 0;

    run_head<2, 1>(x, x1, Wq, bq, Wk, bk, Wv, bv, qw, kw, vw, yw, scratch, partial, att, sbud, 0, 1,  stream);
    run_head<4, 2>(x, x1, Wq, bq, Wk, bk, Wv, bv, qw, kw, vw, yw, scratch, partial, att, sbud, 1, 1,  stream);
    run_head<8, 3>(x, x1, Wq, bq, Wk, bk, Wv, bv, qw, kw, vw, yw, scratch, partial, att, sbud, 2, 8,  stream);
    run_head<16,4>(x, x1, Wq, bq, Wk, bk, Wv, bv, qw, kw, vw, yw, scratch, partial, att, sbud, 3, 64, stream);

    transform_w_kernel<<<(9 * 8 * 256 * 32 + 255) / 256, dim3(256), 0, stream>>>(Wo, Wt);
    to_bf16_kernel<<<2048, dim3(256), 0, stream>>>(att, att_bf, NFULL / 4);
    conv_mfma_kernel<<<dim3(24, 4, BT), dim3(256), 0, stream>>>(att_bf, Wt, bo, out);
}

// Round 5
// 1808.026 us; speedup vs baseline: 4.1444x; 1.1525x over previous
//
#include <hip/hip_runtime.h>
#include <math.h>

#define BT 16
#define CCH 256
#define IH 96
#define IW 96
#define HW (IH*IW)            // 9216
#define DK 64

static const long long WIN   = (long long)BT * HW * DK;   // 9,437,184 elems (one head, all bt)
static const long long NFULL = 4 * WIN;                    // 37,748,736 elems
static const long long WB    = WIN * 2;                    // bytes of one bf16 head buffer

typedef __attribute__((ext_vector_type(8))) short bf16x8;
typedef __attribute__((ext_vector_type(4))) float f32x4;

__device__ __forceinline__ unsigned short f2bf(float f) {
    unsigned int x = __float_as_uint(f);
    unsigned int r = (x + 0x7FFFu + ((x >> 16) & 1u)) >> 16;
    return (unsigned short)r;
}

// ---------------- fused 1x1-conv projections via bf16 MFMA
// Block: M=256 out-ch x N=64 raw pixels, K=256. Writes windowed bf16 layout
// with d-index = pyx*64 + ch for every head (head = och/64).
// NPASS=1: q from x. NPASS=2: k and v from x1 (shared staged X tile).
template<int NPASS>
__global__ __launch_bounds__(256) void proj_mfma_kernel(
    const float* __restrict__ x,
    const float* __restrict__ W0, const float* __restrict__ b0, unsigned short* __restrict__ o0p,
    const float* __restrict__ W1, const float* __restrict__ b1, unsigned short* __restrict__ o1p)
{
    __shared__ alignas(16) unsigned short Xs[64 * 256];   // [px][ch] swizzled, 32 KB
    __shared__ alignas(16) unsigned short Ws[256 * 64];   // [och][k-chunk] swizzled, 32 KB (reused as C-stage)
    int tid = threadIdx.x;
    int p0 = blockIdx.x * 64;
    int bt = blockIdx.z;
    int w = tid >> 6, l = tid & 63, l15 = l & 15, lg = l >> 4;

    // ---- stage X tile: 256 ch x 64 px, fp32 -> bf16, transposed to [px][ch]
    {
        const float* xb = x + (long long)bt * CCH * HW + p0;
        int px = tid & 63, cb = tid >> 6;
        #pragma unroll
        for (int it = 0; it < 16; it++) {
            int c0 = it * 16 + cb * 4;
            float v0 = xb[(long long)(c0 + 0) * HW + px];
            float v1 = xb[(long long)(c0 + 1) * HW + px];
            float v2 = xb[(long long)(c0 + 2) * HW + px];
            float v3 = xb[(long long)(c0 + 3) * HW + px];
            ushort4 u4 = {f2bf(v0), f2bf(v1), f2bf(v2), f2bf(v3)};
            int uu = (c0 >> 3) ^ (px & 31);
            *(ushort4*)((char*)Xs + px * 512 + (uu << 4) + ((c0 >> 2) & 1) * 8) = u4;
        }
    }

    for (int pass = 0; pass < NPASS; pass++) {
        const float* W = pass ? W1 : W0;
        const float* bias = pass ? b1 : b0;
        unsigned short* outp = pass ? o1p : o0p;

        f32x4 acc[4][4];
        #pragma unroll
        for (int i = 0; i < 4; i++)
            #pragma unroll
            for (int j = 0; j < 4; j++) acc[i][j] = (f32x4){0.f, 0.f, 0.f, 0.f};

        for (int kc = 0; kc < CCH; kc += 64) {
            __syncthreads();
            // stage W chunk [256 o][64 k]
            {
                int c4 = (tid & 15) * 4;
                int ob = tid >> 4;
                int uu0 = c4 >> 3, hh = (c4 >> 2) & 1;
                #pragma unroll
                for (int it = 0; it < 16; it++) {
                    int o = it * 16 + ob;
                    float4 wv = *(const float4*)(W + (long long)o * CCH + kc + c4);
                    ushort4 u4 = {f2bf(wv.x), f2bf(wv.y), f2bf(wv.z), f2bf(wv.w)};
                    *(ushort4*)((char*)Ws + o * 128 + ((uu0 ^ (o & 7)) << 4) + hh * 8) = u4;
                }
            }
            __syncthreads();
            #pragma unroll
            for (int kst = 0; kst < 2; kst++) {
                bf16x8 a[4], b[4];
                #pragma unroll
                for (int mf = 0; mf < 4; mf++) {
                    int m = w * 64 + mf * 16 + l15;
                    int uu = (kst * 4 + lg) ^ (m & 7);
                    a[mf] = *(const bf16x8*)((const char*)Ws + m * 128 + (uu << 4));
                }
                #pragma unroll
                for (int nf = 0; nf < 4; nf++) {
                    int px = nf * 16 + l15;
                    int ug = (kc >> 3) + kst * 4 + lg;
                    b[nf] = *(const bf16x8*)((const char*)Xs + px * 512 + ((ug ^ (px & 31)) << 4));
                }
                #pragma unroll
                for (int mf = 0; mf < 4; mf++)
                    #pragma unroll
                    for (int nf = 0; nf < 4; nf++)
                        acc[mf][nf] = __builtin_amdgcn_mfma_f32_16x16x32_bf16(a[mf], b[nf], acc[mf][nf], 0, 0, 0);
            }
        }

        // ---- epilogue: bias, bf16, restage as [px][ch] in Ws, then windowed global write
        __syncthreads();
        #pragma unroll
        for (int mf = 0; mf < 4; mf++) {
            int ch0 = w * 64 + mf * 16 + lg * 4;
            float4 bv = *(const float4*)(bias + ch0);
            #pragma unroll
            for (int nf = 0; nf < 4; nf++) {
                int px = nf * 16 + l15;
                ushort4 u4 = {f2bf(acc[mf][nf][0] + bv.x), f2bf(acc[mf][nf][1] + bv.y),
                              f2bf(acc[mf][nf][2] + bv.z), f2bf(acc[mf][nf][3] + bv.w)};
                int uu = (ch0 >> 3) ^ (px & 31);
                *(ushort4*)((char*)Ws + px * 512 + (uu << 4) + ((ch0 >> 2) & 1) * 8) = u4;
            }
        }
        __syncthreads();
        {
            int cg = tid & 31;
            int h = cg >> 3, lp = h + 1, P = 2 << h;
            int side = 96 >> lp;
            int nwin = side * side;
            long long dlen = (long long)64 << (2 * lp);
            unsigned short* dst = outp + (long long)h * WIN + (long long)bt * nwin * dlen + (cg & 7) * 8;
            #pragma unroll
            for (int it = 0; it < 8; it++) {
                int pxl = it * 8 + (tid >> 5);
                int p = p0 + pxl;
                int y = p / 96, xx = p - y * 96;
                int n = (y >> lp) * side + (xx >> lp);
                int pyx = ((y & (P - 1)) << lp) + (xx & (P - 1));
                int uu = cg ^ (pxl & 31);
                bf16x8 v = *(const bf16x8*)((const char*)Ws + pxl * 512 + (uu << 4));
                *(bf16x8*)(dst + (long long)n * dlen + (long long)pyx * 64) = v;
            }
        }
    }
}

// ---------------- QK^T via bf16 MFMA, 64x64 tile, optional split-K
__global__ __launch_bounds__(256) void qk_mfma_kernel(const unsigned short* __restrict__ qw,
    const unsigned short* __restrict__ kw, float* __restrict__ scores,
    float* __restrict__ partial, int nw, int dlen, float scale, int ksplit,
    int tspan, int bt0)
{
    __shared__ alignas(16) unsigned short Qs[64 * 64];
    __shared__ alignas(16) unsigned short Ks[64 * 64];
    int tid = threadIdx.x;
    int m0 = blockIdx.x * 64, n0 = blockIdx.y * 64;
    int btl = blockIdx.z / ksplit;
    int kidx = blockIdx.z - btl * ksplit;
    int bt = bt0 + btl;
    int dchunk = dlen / ksplit;
    long long kbase = (long long)kidx * dchunk;
    int w = tid >> 6, l = tid & 63, l15 = l & 15, lg = l >> 4;
    f32x4 acc[4];
    #pragma unroll
    for (int nf = 0; nf < 4; nf++) acc[nf] = (f32x4){0.f, 0.f, 0.f, 0.f};

    const unsigned short* qb = qw + ((long long)bt * nw + n0) * dlen + kbase;
    const unsigned short* kb = kw + ((long long)bt * nw + m0) * dlen + kbase;
    int qrows = nw - n0; if (qrows > 64) qrows = 64;
    int krows = nw - m0; if (krows > 64) krows = 64;
    int arow = w * 16 + l15;

    for (int kc = 0; kc < dchunk; kc += 64) {
        if (kc) __syncthreads();
        #pragma unroll
        for (int i = 0; i < 2; i++) {
            int c = tid + i * 256;
            int row = c >> 3, kg = c & 7;
            int kgs = (kg ^ (row & 7)) * 8;
            bf16x8 qv = {0,0,0,0,0,0,0,0};
            bf16x8 kv = {0,0,0,0,0,0,0,0};
            if (row < qrows) qv = *(const bf16x8*)(qb + (long long)row * dlen + kc + kg * 8);
            if (row < krows) kv = *(const bf16x8*)(kb + (long long)row * dlen + kc + kg * 8);
            *(bf16x8*)(Qs + row * 64 + kgs) = qv;
            *(bf16x8*)(Ks + row * 64 + kgs) = kv;
        }
        __syncthreads();
        #pragma unroll
        for (int k0 = 0; k0 < 64; k0 += 32) {
            int kg = (k0 >> 3) + lg;
            bf16x8 a = *(const bf16x8*)(Qs + arow * 64 + (kg ^ (arow & 7)) * 8);
            #pragma unroll
            for (int nf = 0; nf < 4; nf++) {
                int col = nf * 16 + l15;
                bf16x8 b = *(const bf16x8*)(Ks + col * 64 + (kg ^ (col & 7)) * 8);
                acc[nf] = __builtin_amdgcn_mfma_f32_16x16x32_bf16(a, b, acc[nf], 0, 0, 0);
            }
        }
    }

    if (ksplit == 1) {
        #pragma unroll
        for (int nf = 0; nf < 4; nf++) {
            int c = m0 + nf * 16 + l15;
            #pragma unroll
            for (int reg = 0; reg < 4; reg++) {
                int r = n0 + w * 16 + lg * 4 + reg;
                if (r < nw && c < nw)
                    scores[((long long)btl * nw + r) * nw + c] = acc[nf][reg] * scale;
            }
        }
    } else {
        #pragma unroll
        for (int nf = 0; nf < 4; nf++) {
            int c = m0 + nf * 16 + l15;
            #pragma unroll
            for (int reg = 0; reg < 4; reg++) {
                int r = n0 + w * 16 + lg * 4 + reg;
                partial[(((long long)btl * ksplit + kidx) * tspan + r) * tspan + c] = acc[nf][reg];
            }
        }
    }
}

__global__ __launch_bounds__(256) void qk_reduce_kernel(const float* __restrict__ partial,
    float* __restrict__ scores, int nw, int tspan, int ksplit, float scale, int btc)
{
    long long idx = (long long)blockIdx.x * 256 + threadIdx.x;
    if (idx >= (long long)btc * nw * nw) return;
    int m = (int)(idx % nw);
    long long t = idx / nw;
    int n = (int)(t % nw);
    int btl = (int)(t / nw);
    float s = 0.f;
    for (int k = 0; k < ksplit; k++)
        s += partial[(((long long)btl * ksplit + k) * tspan + n) * tspan + m];
    scores[((long long)btl * nw + n) * nw + m] = s * scale;
}

// ---------------- row softmax: fp32 scores in, bf16 P out
__global__ __launch_bounds__(256) void softmax_kernel(const float* __restrict__ scores,
    unsigned short* __restrict__ pb16, int nw)
{
    __shared__ float red[8];
    int n = blockIdx.x, btl = blockIdx.y;
    const float* row = scores + ((long long)btl * nw + n) * nw;
    unsigned short* prow = pb16 + ((long long)btl * nw + n) * nw;
    int tid = threadIdx.x;
    float vals[9];
    float lmax = -3e38f;
    #pragma unroll
    for (int it = 0; it < 9; it++) {
        int m = tid + it * 256;
        if (m < nw) { vals[it] = row[m]; lmax = fmaxf(lmax, vals[it]); }
        else vals[it] = -3e38f;
    }
    #pragma unroll
    for (int o = 32; o > 0; o >>= 1) lmax = fmaxf(lmax, __shfl_down(lmax, o, 64));
    if ((tid & 63) == 0) red[tid >> 6] = lmax;
    __syncthreads();
    float rmax = fmaxf(fmaxf(red[0], red[1]), fmaxf(red[2], red[3]));
    __syncthreads();
    float lsum = 0.f;
    #pragma unroll
    for (int it = 0; it < 9; it++) {
        int m = tid + it * 256;
        if (m < nw) { vals[it] = __expf(vals[it] - rmax); lsum += vals[it]; }
    }
    #pragma unroll
    for (int o = 32; o > 0; o >>= 1) lsum += __shfl_down(lsum, o, 64);
    if ((tid & 63) == 0) red[tid >> 6] = lsum;
    __syncthreads();
    float rsum = red[0] + red[1] + red[2] + red[3];
    float inv = 1.f / rsum;
    #pragma unroll
    for (int it = 0; it < 9; it++) {
        int m = tid + it * 256;
        if (m < nw) prow[m] = f2bf(vals[it] * inv);
    }
}

// ---------------- P @ V via bf16 MFMA; 64(n) x 64(d) tile, bf16 output
__global__ __launch_bounds__(256) void pv_mfma_kernel(const unsigned short* __restrict__ p,
    const unsigned short* __restrict__ vw, unsigned short* __restrict__ yw, int nw, int dlen, int bt0)
{
    __shared__ alignas(16) unsigned short Ps[64 * 64];
    __shared__ alignas(16) unsigned short Vt[64 * 64];
    int tid = threadIdx.x;
    int d0 = blockIdx.x * 64, n0 = blockIdx.y * 64;
    int btl = blockIdx.z;
    int bt = bt0 + btl;
    int w = tid >> 6, l = tid & 63, l15 = l & 15, lg = l >> 4;
    f32x4 acc[4];
    #pragma unroll
    for (int nf = 0; nf < 4; nf++) acc[nf] = (f32x4){0.f, 0.f, 0.f, 0.f};

    const unsigned short* pb = p + ((long long)btl * nw + n0) * nw;
    const unsigned short* vb = vw + (long long)bt * nw * dlen + d0;
    int prows = nw - n0; if (prows > 64) prows = 64;
    int arow = w * 16 + l15;
    int du = tid & 15, mu = tid >> 4;

    for (int mc = 0; mc < nw; mc += 64) {
        if (mc) __syncthreads();
        int mrem = nw - mc;
        #pragma unroll
        for (int i = 0; i < 2; i++) {
            int c = tid + i * 256;
            int row = c >> 3, kg = c & 7;
            bf16x8 v = {0,0,0,0,0,0,0,0};
            if (row < prows) {
                int mb = kg * 8;
                if (mb + 8 <= mrem) v = *(const bf16x8*)(pb + (long long)row * nw + mc + mb);
                else if (mb < mrem) {
                    for (int e = 0; e < mrem - mb; e++)
                        v[e] = (short)pb[(long long)row * nw + mc + mb + e];
                }
            }
            *(bf16x8*)(Ps + row * 64 + (kg ^ (row & 7)) * 8) = v;
        }
        {
            ushort4 vv[4];
            #pragma unroll
            for (int i = 0; i < 4; i++) {
                int m = mc + mu * 4 + i;
                if (m < nw) vv[i] = *(const ushort4*)(vb + (long long)m * dlen + du * 4);
                else vv[i] = (ushort4){0, 0, 0, 0};
            }
            #pragma unroll
            for (int j = 0; j < 4; j++) {
                int d = du * 4 + j;
                int byte = d * 128 + (((mu >> 1) ^ (d & 7)) * 16) + (mu & 1) * 8;
                ushort4 tj;
                tj.x = ((const unsigned short*)&vv[0])[j];
                tj.y = ((const unsigned short*)&vv[1])[j];
                tj.z = ((const unsigned short*)&vv[2])[j];
                tj.w = ((const unsigned short*)&vv[3])[j];
                *(ushort4*)((char*)Vt + byte) = tj;
            }
        }
        __syncthreads();
        #pragma unroll
        for (int k0 = 0; k0 < 64; k0 += 32) {
            int kg = (k0 >> 3) + lg;
            bf16x8 a = *(const bf16x8*)(Ps + arow * 64 + (kg ^ (arow & 7)) * 8);
            #pragma unroll
            for (int nf = 0; nf < 4; nf++) {
                int col = nf * 16 + l15;
                bf16x8 b = *(const bf16x8*)(Vt + col * 64 + (kg ^ (col & 7)) * 8);
                acc[nf] = __builtin_amdgcn_mfma_f32_16x16x32_bf16(a, b, acc[nf], 0, 0, 0);
            }
        }
    }

    #pragma unroll
    for (int nf = 0; nf < 4; nf++) {
        int d = d0 + nf * 16 + l15;
        #pragma unroll
        for (int reg = 0; reg < 4; reg++) {
            int n = n0 + w * 16 + lg * 4 + reg;
            if (n < nw)
                yw[((long long)bt * nw + n) * dlen + d] = f2bf(acc[nf][reg]);
        }
    }
}

// ---------------- unwindow scatter (bf16 -> bf16), d-index = pyx*64 + ch
template<int P>
__global__ __launch_bounds__(256) void unwindow_kernel(const unsigned short* __restrict__ ywb,
    unsigned short* __restrict__ att, int head)
{
    constexpr int SIDE = 96 / P;
    constexpr int DLEN = DK * P * P;
    long long idx = (long long)blockIdx.x * 256 + threadIdx.x;
    if (idx >= (long long)BT * DK * HW) return;
    int x = (int)(idx % IW);
    long long t = idx / IW;
    int y = (int)(t % IH); t /= IH;
    int ch = (int)(t % DK);
    int bt = (int)(t / DK);
    int oh = y / P, py = y & (P - 1), ow = x / P, px = x & (P - 1);
    int n = oh * SIDE + ow;
    int dd = (py * P + px) * 64 + ch;
    att[(((long long)(bt * CCH + head * DK + ch)) * IH + y) * IW + x] =
        ywb[((long long)bt * (SIDE * SIDE) + n) * DLEN + dd];
}

// ---------------- Wo fp32 [o][c][3][3] -> bf16 Wt[t][cc][o][cl]
__global__ __launch_bounds__(256) void transform_w_kernel(const float* __restrict__ Wo,
    unsigned short* __restrict__ Wt)
{
    int idx = blockIdx.x * 256 + threadIdx.x;
    if (idx >= 9 * 8 * 256 * 32) return;
    int cl = idx & 31;
    int o  = (idx >> 5) & 255;
    int cc = (idx >> 13) & 7;
    int t  = idx >> 16;
    int dy = t / 3, dx = t - dy * 3;
    int c = cc * 32 + cl;
    Wt[idx] = f2bf(Wo[((long long)(o * CCH + c) * 3 + dy) * 3 + dx]);
}

// ---------------- 3x3 conv via bf16 MFMA implicit GEMM + bias + LeakyReLU
__global__ __launch_bounds__(256) void conv_mfma_kernel(
    const unsigned short* __restrict__ att_bf, const unsigned short* __restrict__ Wt,
    const float* __restrict__ bo, float* __restrict__ out)
{
    __shared__ alignas(16) unsigned short in_t[6 * 104 * 32];   // [row][px][ch32], px-swizzled
    int tid = threadIdx.x;
    int ytile = blockIdx.x, otile = blockIdx.y, bt = blockIdx.z;
    int ybase = ytile * 4, o0 = otile * 64;
    int w = tid >> 6, l = tid & 63;
    int l15 = l & 15, lg = l >> 4;

    f32x4 acc[4][6];
    #pragma unroll
    for (int mf = 0; mf < 4; mf++)
        #pragma unroll
        for (int nf = 0; nf < 6; nf++)
            acc[mf][nf] = (f32x4){0.f, 0.f, 0.f, 0.f};

    for (int it = tid; it < 96; it += 256) {
        int side = it / 48, rem = it - side * 48;
        int row = rem >> 3, cg = rem & 7;
        int px = side ? 97 : 0;
        int byte = (((row * 104 + px) * 64) + cg * 8) ^ ((px & 3) << 4);
        ushort4 z = {0, 0, 0, 0};
        *(ushort4*)((char*)in_t + byte) = z;
    }

    const unsigned short* ab = att_bf + (long long)bt * CCH * HW;

    for (int cc = 0; cc < 8; cc++) {
        __syncthreads();
        for (int it = tid; it < 1152; it += 256) {
            int x4 = it % 24;
            int cg = (it / 24) & 7;
            int row = it / 192;
            int ya = ybase + row - 1;
            ushort4 v0, v1, v2, v3;
            if (ya >= 0 && ya < IH) {
                const unsigned short* p = ab + (long long)(cc * 32 + cg * 4) * HW + ya * IW + x4 * 4;
                v0 = *(const ushort4*)(p);
                v1 = *(const ushort4*)(p + HW);
                v2 = *(const ushort4*)(p + 2 * HW);
                v3 = *(const ushort4*)(p + 3 * HW);
            } else {
                v0 = v1 = v2 = v3 = (ushort4){0, 0, 0, 0};
            }
            int pxb = x4 * 4 + 1;
            int rowoff = row * 104;
            ushort4 t0 = {v0.x, v1.x, v2.x, v3.x};
            ushort4 t1 = {v0.y, v1.y, v2.y, v3.y};
            ushort4 t2 = {v0.z, v1.z, v2.z, v3.z};
            ushort4 t3 = {v0.w, v1.w, v2.w, v3.w};
            int b0 = (((rowoff + pxb + 0) * 64) + cg * 8) ^ (((pxb + 0) & 3) << 4);
            int b1 = (((rowoff + pxb + 1) * 64) + cg * 8) ^ (((pxb + 1) & 3) << 4);
            int b2 = (((rowoff + pxb + 2) * 64) + cg * 8) ^ (((pxb + 2) & 3) << 4);
            int b3 = (((rowoff + pxb + 3) * 64) + cg * 8) ^ (((pxb + 3) & 3) << 4);
            *(ushort4*)((char*)in_t + b0) = t0;
            *(ushort4*)((char*)in_t + b1) = t1;
            *(ushort4*)((char*)in_t + b2) = t2;
            *(ushort4*)((char*)in_t + b3) = t3;
        }
        __syncthreads();

        for (int t = 0; t < 9; t++) {
            int dy = t / 3, dx = t - dy * 3;
            bf16x8 a[4];
            const unsigned short* wp = Wt + ((long long)(t * 8 + cc) * 256 + o0) * 32 + lg * 8;
            #pragma unroll
            for (int mf = 0; mf < 4; mf++)
                a[mf] = *(const bf16x8*)(wp + (mf * 16 + l15) * 32);
            int rowoff = (w + dy) * 104;
            #pragma unroll
            for (int nf = 0; nf < 6; nf++) {
                int px = nf * 16 + l15 + dx;
                int byte = (((rowoff + px) * 64) + lg * 16) ^ ((px & 3) << 4);
                bf16x8 b = *(const bf16x8*)((const char*)in_t + byte);
                #pragma unroll
                for (int mf = 0; mf < 4; mf++)
                    acc[mf][nf] = __builtin_amdgcn_mfma_f32_16x16x32_bf16(a[mf], b, acc[mf][nf], 0, 0, 0);
            }
        }
    }

    int y = ybase + w;
    #pragma unroll
    for (int mf = 0; mf < 4; mf++) {
        #pragma unroll
        for (int reg = 0; reg < 4; reg++) {
            int o = o0 + mf * 16 + lg * 4 + reg;
            float bv = bo[o];
            long long obase = (((long long)bt * CCH + o) * IH + y) * IW;
            #pragma unroll
            for (int nf = 0; nf < 6; nf++) {
                int x = nf * 16 + l15;
                float v = acc[mf][nf][reg] + bv;
                out[obase + x] = v >= 0.f ? v : 0.2f * v;
            }
        }
    }
}

// ---------------- per-head host driver
template<int P, int LOGP>
static void run_head(const unsigned short* qw, const unsigned short* kw, const unsigned short* vw,
                     unsigned short* ywb, char* scratch, float* partial, unsigned short* att_bf,
                     size_t sbud, int head, int ks, hipStream_t stream)
{
    constexpr int SIDE = 96 / P;
    constexpr int NWIN = SIDE * SIDE;
    constexpr int DLEN = DK * P * P;
    int nw = NWIN, dlen = DLEN;
    float scale = 1.0f / sqrtf((float)dlen);
    int nt = (nw + 63) / 64;
    int tspan = nt * 64;
    dim3 blk(256);

    int btc = BT;
    while (btc > 1 && (size_t)btc * nw * nw * 6 > sbud) btc >>= 1;

    float* scores = (float*)scratch;
    unsigned short* pb16 = (unsigned short*)(scratch + (size_t)btc * nw * nw * 4);

    for (int bt0 = 0; bt0 < BT; bt0 += btc) {
        qk_mfma_kernel<<<dim3(nt, nt, btc * ks), blk, 0, stream>>>(qw, kw, scores, partial,
                                                                   nw, dlen, scale, ks, tspan, bt0);
        if (ks > 1) {
            long long tot = (long long)btc * nw * nw;
            qk_reduce_kernel<<<(unsigned)((tot + 255) / 256), blk, 0, stream>>>(
                partial, scores, nw, tspan, ks, scale, btc);
        }
        softmax_kernel<<<dim3(nw, btc), blk, 0, stream>>>(scores, pb16, nw);
        pv_mfma_kernel<<<dim3(dlen / 64, nt, btc), blk, 0, stream>>>(pb16, vw, ywb, nw, dlen, bt0);
    }
    unwindow_kernel<P><<<36864, blk, 0, stream>>>(ywb, att_bf, head);
}

extern "C" void kernel_launch(void* const* d_in, const int* in_sizes, int n_in,
                              void* d_out, int out_size, void* d_ws, size_t ws_size,
                              hipStream_t stream) {
    const float* x  = (const float*)d_in[0];
    const float* x1 = (const float*)d_in[1];
    const float* Wq = (const float*)d_in[2];
    const float* bq = (const float*)d_in[3];
    const float* Wk = (const float*)d_in[4];
    const float* bk = (const float*)d_in[5];
    const float* Wv = (const float*)d_in[6];
    const float* bv = (const float*)d_in[7];
    const float* Wo = (const float*)d_in[8];
    const float* bo = (const float*)d_in[9];
    float* out = (float*)d_out;

    // workspace layout (bytes): qfull 4WB | kfull 4WB | vfull 4WB | ywb 1WB | att_bf 4WB | scratch
    unsigned short* qfull  = (unsigned short*)d_ws;
    unsigned short* kfull  = qfull + NFULL;
    unsigned short* vfull  = kfull + NFULL;
    unsigned short* ywb    = vfull + NFULL;           // one head's PV output (bf16)
    float*          partial = (float*)ywb;            // split-K partials overlay (<= 1 WB)
    unsigned short* att_bf = ywb + WIN;               // concat attention output (bf16)
    char*           scratch = (char*)(att_bf + NFULL);
    unsigned short* Wt     = ywb;                     // conv weights overlay (ywb dead after heads)

    size_t fixed = (size_t)(17 * WB);
    size_t sbud = (ws_size > fixed) ? ws_size - fixed : 0;

    dim3 blk(256);
    proj_mfma_kernel<1><<<dim3(144, 1, BT), blk, 0, stream>>>(x,  Wq, bq, qfull, Wq, bq, qfull);
    proj_mfma_kernel<2><<<dim3(144, 1, BT), blk, 0, stream>>>(x1, Wk, bk, kfull, Wv, bv, vfull);

    run_head<2, 1>(qfull,           kfull,           vfull,           ywb, scratch, partial, att_bf, sbud, 0, 1,  stream);
    run_head<4, 2>(qfull + WIN,     kfull + WIN,     vfull + WIN,     ywb, scratch, partial, att_bf, sbud, 1, 1,  stream);
    run_head<8, 3>(qfull + 2 * WIN, kfull + 2 * WIN, vfull + 2 * WIN, ywb, scratch, partial, att_bf, sbud, 2, 8,  stream);
    run_head<16,4>(qfull + 3 * WIN, kfull + 3 * WIN, vfull + 3 * WIN, ywb, scratch, partial, att_bf, sbud, 3, 64, stream);

    transform_w_kernel<<<(9 * 8 * 256 * 32 + 255) / 256, blk, 0, stream>>>(Wo, Wt);
    conv_mfma_kernel<<<dim3(24, 4, BT), blk, 0, stream>>>(att_bf, Wt, bo, out);
}

// Round 6
// 1272.802 us; speedup vs baseline: 5.8872x; 1.4205x over previous
//
#include <hip/hip_runtime.h>
#include <math.h>

#define BT 16
#define CCH 256
#define IH 96
#define IW 96
#define HW (IH*IW)            // 9216
#define DK 64

static const long long WIN   = (long long)BT * HW * DK;   // 9,437,184 elems (one head, all bt)
static const long long NFULL = 4 * WIN;                    // 37,748,736 elems
static const long long WB    = WIN * 2;                    // bytes of one bf16 head buffer

typedef __attribute__((ext_vector_type(8))) short bf16x8;
typedef __attribute__((ext_vector_type(4))) float f32x4;

__device__ __forceinline__ unsigned short f2bf(float f) {
    unsigned int x = __float_as_uint(f);
    unsigned int r = (x + 0x7FFFu + ((x >> 16) & 1u)) >> 16;
    return (unsigned short)r;
}

// ---------------- transpose+convert: x[bt][c][hw] fp32 -> xT[bt][hw][c] bf16
__global__ __launch_bounds__(256) void transpose_cvt_kernel(const float* __restrict__ x,
    unsigned short* __restrict__ xT)
{
    __shared__ float Ls[64][65];
    int tid = threadIdx.x;
    int p0 = blockIdx.x * 64;      // 144 tiles of 64 px
    int c0 = blockIdx.y * 64;      // 4 tiles of 64 ch
    int bt = blockIdx.z;
    int px4 = (tid & 15) * 4, chb = tid >> 4;
    const float* xb = x + ((long long)(bt * CCH + c0) * HW) + p0;
    #pragma unroll
    for (int it = 0; it < 4; it++) {
        int ch = chb + it * 16;
        float4 v = *(const float4*)(xb + (long long)ch * HW + px4);
        Ls[px4 + 0][ch] = v.x;
        Ls[px4 + 1][ch] = v.y;
        Ls[px4 + 2][ch] = v.z;
        Ls[px4 + 3][ch] = v.w;
    }
    __syncthreads();
    int px = tid >> 2, cg = (tid & 3) * 16;
    unsigned short* dst = xT + ((long long)bt * HW + p0 + px) * CCH + c0 + cg;
    #pragma unroll
    for (int half = 0; half < 2; half++) {
        ushort4 a, b;
        a.x = f2bf(Ls[px][cg + half * 8 + 0]);
        a.y = f2bf(Ls[px][cg + half * 8 + 1]);
        a.z = f2bf(Ls[px][cg + half * 8 + 2]);
        a.w = f2bf(Ls[px][cg + half * 8 + 3]);
        b.x = f2bf(Ls[px][cg + half * 8 + 4]);
        b.y = f2bf(Ls[px][cg + half * 8 + 5]);
        b.z = f2bf(Ls[px][cg + half * 8 + 6]);
        b.w = f2bf(Ls[px][cg + half * 8 + 7]);
        *(ushort4*)(dst + half * 8)     = a;
        *(ushort4*)(dst + half * 8 + 4) = b;
    }
}

// ---------------- Wq/Wk/Wv fp32 -> bf16 (same [o][c] layout), packed [3][256][256]
__global__ __launch_bounds__(256) void cvtw_kernel(const float* __restrict__ Wq,
    const float* __restrict__ Wk, const float* __restrict__ Wv,
    unsigned short* __restrict__ Wb)
{
    int idx = blockIdx.x * 256 + threadIdx.x;
    if (idx >= 3 * 16384) return;
    const float* src = idx < 16384 ? Wq : (idx < 32768 ? Wk : Wv);
    int off = (idx & 16383) * 4;
    float4 v = *(const float4*)(src + off);
    ushort4 u = {f2bf(v.x), f2bf(v.y), f2bf(v.z), f2bf(v.w)};
    *(ushort4*)(Wb + (long long)idx * 4) = u;
}

// ---------------- fused 1x1-conv projections via bf16 MFMA (bf16 inputs)
// Block: M=256 out-ch x N=64 raw pixels, K=256. Writes windowed bf16 layout
// with d-index = pyx*64 + ch. NPASS=1: q. NPASS=2: k and v (shared X tile).
template<int NPASS>
__global__ __launch_bounds__(256) void proj_mfma_kernel(
    const unsigned short* __restrict__ xT,
    const unsigned short* __restrict__ Wb0, const float* __restrict__ b0, unsigned short* __restrict__ o0p,
    const unsigned short* __restrict__ Wb1, const float* __restrict__ b1, unsigned short* __restrict__ o1p)
{
    __shared__ alignas(16) unsigned short Xs[64 * 256];   // [px][ch] swizzled, 32 KB
    __shared__ alignas(16) unsigned short Ws[256 * 64];   // [och][k-chunk] swizzled, 32 KB (reused as C-stage)
    int tid = threadIdx.x;
    int p0 = blockIdx.x * 64;
    int bt = blockIdx.z;
    int w = tid >> 6, l = tid & 63, l15 = l & 15, lg = l >> 4;

    // ---- stage X tile [64px][256ch] via contiguous bf16x8 loads
    {
        const unsigned short* xb = xT + ((long long)bt * HW + p0) * CCH;
        #pragma unroll
        for (int it = 0; it < 8; it++) {
            int flat = tid + it * 256;
            int px = flat >> 5, cg = flat & 31;
            bf16x8 v = *(const bf16x8*)(xb + (long long)px * CCH + cg * 8);
            *(bf16x8*)((char*)Xs + px * 512 + ((cg ^ (px & 31)) << 4)) = v;
        }
    }

    for (int pass = 0; pass < NPASS; pass++) {
        const unsigned short* W = pass ? Wb1 : Wb0;
        const float* bias = pass ? b1 : b0;
        unsigned short* outp = pass ? o1p : o0p;

        f32x4 acc[4][4];
        #pragma unroll
        for (int i = 0; i < 4; i++)
            #pragma unroll
            for (int j = 0; j < 4; j++) acc[i][j] = (f32x4){0.f, 0.f, 0.f, 0.f};

        for (int kc = 0; kc < CCH; kc += 64) {
            __syncthreads();
            // stage W chunk [256 o][64 k] via contiguous bf16x8 loads
            #pragma unroll
            for (int it = 0; it < 8; it++) {
                int flat = tid + it * 256;
                int o = flat >> 3, kg = flat & 7;
                bf16x8 v = *(const bf16x8*)(W + o * 256 + kc + kg * 8);
                *(bf16x8*)((char*)Ws + o * 128 + ((kg ^ (o & 7)) << 4)) = v;
            }
            __syncthreads();
            #pragma unroll
            for (int kst = 0; kst < 2; kst++) {
                bf16x8 a[4], b[4];
                #pragma unroll
                for (int mf = 0; mf < 4; mf++) {
                    int m = w * 64 + mf * 16 + l15;
                    int uu = (kst * 4 + lg) ^ (m & 7);
                    a[mf] = *(const bf16x8*)((const char*)Ws + m * 128 + (uu << 4));
                }
                #pragma unroll
                for (int nf = 0; nf < 4; nf++) {
                    int px = nf * 16 + l15;
                    int ug = (kc >> 3) + kst * 4 + lg;
                    b[nf] = *(const bf16x8*)((const char*)Xs + px * 512 + ((ug ^ (px & 31)) << 4));
                }
                #pragma unroll
                for (int mf = 0; mf < 4; mf++)
                    #pragma unroll
                    for (int nf = 0; nf < 4; nf++)
                        acc[mf][nf] = __builtin_amdgcn_mfma_f32_16x16x32_bf16(a[mf], b[nf], acc[mf][nf], 0, 0, 0);
            }
        }

        // ---- epilogue: bias, bf16, restage as [px][ch] in Ws, then windowed global write
        __syncthreads();
        #pragma unroll
        for (int mf = 0; mf < 4; mf++) {
            int ch0 = w * 64 + mf * 16 + lg * 4;
            float4 bv = *(const float4*)(bias + ch0);
            #pragma unroll
            for (int nf = 0; nf < 4; nf++) {
                int px = nf * 16 + l15;
                ushort4 u4 = {f2bf(acc[mf][nf][0] + bv.x), f2bf(acc[mf][nf][1] + bv.y),
                              f2bf(acc[mf][nf][2] + bv.z), f2bf(acc[mf][nf][3] + bv.w)};
                int uu = (ch0 >> 3) ^ (px & 31);
                *(ushort4*)((char*)Ws + px * 512 + (uu << 4) + ((ch0 >> 2) & 1) * 8) = u4;
            }
        }
        __syncthreads();
        {
            int cg = tid & 31;
            int h = cg >> 3, lp = h + 1, P = 2 << h;
            int side = 96 >> lp;
            int nwin = side * side;
            long long dlen = (long long)64 << (2 * lp);
            unsigned short* dst = outp + (long long)h * WIN + (long long)bt * nwin * dlen + (cg & 7) * 8;
            #pragma unroll
            for (int it = 0; it < 8; it++) {
                int pxl = it * 8 + (tid >> 5);
                int p = p0 + pxl;
                int y = p / 96, xx = p - y * 96;
                int n = (y >> lp) * side + (xx >> lp);
                int pyx = ((y & (P - 1)) << lp) + (xx & (P - 1));
                int uu = cg ^ (pxl & 31);
                bf16x8 v = *(const bf16x8*)((const char*)Ws + pxl * 512 + (uu << 4));
                *(bf16x8*)(dst + (long long)n * dlen + (long long)pyx * 64) = v;
            }
        }
    }
}

// ---------------- QK^T via bf16 MFMA, 64x64 tile, optional split-K
__global__ __launch_bounds__(256) void qk_mfma_kernel(const unsigned short* __restrict__ qw,
    const unsigned short* __restrict__ kw, float* __restrict__ scores,
    float* __restrict__ partial, int nw, int dlen, float scale, int ksplit,
    int tspan, int bt0)
{
    __shared__ alignas(16) unsigned short Qs[64 * 64];
    __shared__ alignas(16) unsigned short Ks[64 * 64];
    int tid = threadIdx.x;
    int m0 = blockIdx.x * 64, n0 = blockIdx.y * 64;
    int btl = blockIdx.z / ksplit;
    int kidx = blockIdx.z - btl * ksplit;
    int bt = bt0 + btl;
    int dchunk = dlen / ksplit;
    long long kbase = (long long)kidx * dchunk;
    int w = tid >> 6, l = tid & 63, l15 = l & 15, lg = l >> 4;
    f32x4 acc[4];
    #pragma unroll
    for (int nf = 0; nf < 4; nf++) acc[nf] = (f32x4){0.f, 0.f, 0.f, 0.f};

    const unsigned short* qb = qw + ((long long)bt * nw + n0) * dlen + kbase;
    const unsigned short* kb = kw + ((long long)bt * nw + m0) * dlen + kbase;
    int qrows = nw - n0; if (qrows > 64) qrows = 64;
    int krows = nw - m0; if (krows > 64) krows = 64;
    int arow = w * 16 + l15;

    for (int kc = 0; kc < dchunk; kc += 64) {
        if (kc) __syncthreads();
        #pragma unroll
        for (int i = 0; i < 2; i++) {
            int c = tid + i * 256;
            int row = c >> 3, kg = c & 7;
            int kgs = (kg ^ (row & 7)) * 8;
            bf16x8 qv = {0,0,0,0,0,0,0,0};
            bf16x8 kv = {0,0,0,0,0,0,0,0};
            if (row < qrows) qv = *(const bf16x8*)(qb + (long long)row * dlen + kc + kg * 8);
            if (row < krows) kv = *(const bf16x8*)(kb + (long long)row * dlen + kc + kg * 8);
            *(bf16x8*)(Qs + row * 64 + kgs) = qv;
            *(bf16x8*)(Ks + row * 64 + kgs) = kv;
        }
        __syncthreads();
        #pragma unroll
        for (int k0 = 0; k0 < 64; k0 += 32) {
            int kg = (k0 >> 3) + lg;
            bf16x8 a = *(const bf16x8*)(Qs + arow * 64 + (kg ^ (arow & 7)) * 8);
            #pragma unroll
            for (int nf = 0; nf < 4; nf++) {
                int col = nf * 16 + l15;
                bf16x8 b = *(const bf16x8*)(Ks + col * 64 + (kg ^ (col & 7)) * 8);
                acc[nf] = __builtin_amdgcn_mfma_f32_16x16x32_bf16(a, b, acc[nf], 0, 0, 0);
            }
        }
    }

    if (ksplit == 1) {
        #pragma unroll
        for (int nf = 0; nf < 4; nf++) {
            int c = m0 + nf * 16 + l15;
            #pragma unroll
            for (int reg = 0; reg < 4; reg++) {
                int r = n0 + w * 16 + lg * 4 + reg;
                if (r < nw && c < nw)
                    scores[((long long)btl * nw + r) * nw + c] = acc[nf][reg] * scale;
            }
        }
    } else {
        #pragma unroll
        for (int nf = 0; nf < 4; nf++) {
            int c = m0 + nf * 16 + l15;
            #pragma unroll
            for (int reg = 0; reg < 4; reg++) {
                int r = n0 + w * 16 + lg * 4 + reg;
                partial[(((long long)btl * ksplit + kidx) * tspan + r) * tspan + c] = acc[nf][reg];
            }
        }
    }
}

__global__ __launch_bounds__(256) void qk_reduce_kernel(const float* __restrict__ partial,
    float* __restrict__ scores, int nw, int tspan, int ksplit, float scale, int btc)
{
    long long idx = (long long)blockIdx.x * 256 + threadIdx.x;
    if (idx >= (long long)btc * nw * nw) return;
    int m = (int)(idx % nw);
    long long t = idx / nw;
    int n = (int)(t % nw);
    int btl = (int)(t / nw);
    float s = 0.f;
    for (int k = 0; k < ksplit; k++)
        s += partial[(((long long)btl * ksplit + k) * tspan + n) * tspan + m];
    scores[((long long)btl * nw + n) * nw + m] = s * scale;
}

// ---------------- row softmax: fp32 scores in, bf16 P out
__global__ __launch_bounds__(256) void softmax_kernel(const float* __restrict__ scores,
    unsigned short* __restrict__ pb16, int nw)
{
    __shared__ float red[8];
    int n = blockIdx.x, btl = blockIdx.y;
    const float* row = scores + ((long long)btl * nw + n) * nw;
    unsigned short* prow = pb16 + ((long long)btl * nw + n) * nw;
    int tid = threadIdx.x;
    float vals[9];
    float lmax = -3e38f;
    #pragma unroll
    for (int it = 0; it < 9; it++) {
        int m = tid + it * 256;
        if (m < nw) { vals[it] = row[m]; lmax = fmaxf(lmax, vals[it]); }
        else vals[it] = -3e38f;
    }
    #pragma unroll
    for (int o = 32; o > 0; o >>= 1) lmax = fmaxf(lmax, __shfl_down(lmax, o, 64));
    if ((tid & 63) == 0) red[tid >> 6] = lmax;
    __syncthreads();
    float rmax = fmaxf(fmaxf(red[0], red[1]), fmaxf(red[2], red[3]));
    __syncthreads();
    float lsum = 0.f;
    #pragma unroll
    for (int it = 0; it < 9; it++) {
        int m = tid + it * 256;
        if (m < nw) { vals[it] = __expf(vals[it] - rmax); lsum += vals[it]; }
    }
    #pragma unroll
    for (int o = 32; o > 0; o >>= 1) lsum += __shfl_down(lsum, o, 64);
    if ((tid & 63) == 0) red[tid >> 6] = lsum;
    __syncthreads();
    float rsum = red[0] + red[1] + red[2] + red[3];
    float inv = 1.f / rsum;
    #pragma unroll
    for (int it = 0; it < 9; it++) {
        int m = tid + it * 256;
        if (m < nw) prow[m] = f2bf(vals[it] * inv);
    }
}

// ---------------- P @ V via bf16 MFMA; 64(n) x 64(d) tile, bf16 output
__global__ __launch_bounds__(256) void pv_mfma_kernel(const unsigned short* __restrict__ p,
    const unsigned short* __restrict__ vw, unsigned short* __restrict__ yw, int nw, int dlen, int bt0)
{
    __shared__ alignas(16) unsigned short Ps[64 * 64];
    __shared__ alignas(16) unsigned short Vt[64 * 64];
    int tid = threadIdx.x;
    int d0 = blockIdx.x * 64, n0 = blockIdx.y * 64;
    int btl = blockIdx.z;
    int bt = bt0 + btl;
    int w = tid >> 6, l = tid & 63, l15 = l & 15, lg = l >> 4;
    f32x4 acc[4];
    #pragma unroll
    for (int nf = 0; nf < 4; nf++) acc[nf] = (f32x4){0.f, 0.f, 0.f, 0.f};

    const unsigned short* pb = p + ((long long)btl * nw + n0) * nw;
    const unsigned short* vb = vw + (long long)bt * nw * dlen + d0;
    int prows = nw - n0; if (prows > 64) prows = 64;
    int arow = w * 16 + l15;
    int du = tid & 15, mu = tid >> 4;

    for (int mc = 0; mc < nw; mc += 64) {
        if (mc) __syncthreads();
        int mrem = nw - mc;
        #pragma unroll
        for (int i = 0; i < 2; i++) {
            int c = tid + i * 256;
            int row = c >> 3, kg = c & 7;
            bf16x8 v = {0,0,0,0,0,0,0,0};
            if (row < prows) {
                int mb = kg * 8;
                if (mb + 8 <= mrem) v = *(const bf16x8*)(pb + (long long)row * nw + mc + mb);
                else if (mb < mrem) {
                    for (int e = 0; e < mrem - mb; e++)
                        v[e] = (short)pb[(long long)row * nw + mc + mb + e];
                }
            }
            *(bf16x8*)(Ps + row * 64 + (kg ^ (row & 7)) * 8) = v;
        }
        {
            ushort4 vv[4];
            #pragma unroll
            for (int i = 0; i < 4; i++) {
                int m = mc + mu * 4 + i;
                if (m < nw) vv[i] = *(const ushort4*)(vb + (long long)m * dlen + du * 4);
                else vv[i] = (ushort4){0, 0, 0, 0};
            }
            #pragma unroll
            for (int j = 0; j < 4; j++) {
                int d = du * 4 + j;
                int byte = d * 128 + (((mu >> 1) ^ (d & 7)) * 16) + (mu & 1) * 8;
                ushort4 tj;
                tj.x = ((const unsigned short*)&vv[0])[j];
                tj.y = ((const unsigned short*)&vv[1])[j];
                tj.z = ((const unsigned short*)&vv[2])[j];
                tj.w = ((const unsigned short*)&vv[3])[j];
                *(ushort4*)((char*)Vt + byte) = tj;
            }
        }
        __syncthreads();
        #pragma unroll
        for (int k0 = 0; k0 < 64; k0 += 32) {
            int kg = (k0 >> 3) + lg;
            bf16x8 a = *(const bf16x8*)(Ps + arow * 64 + (kg ^ (arow & 7)) * 8);
            #pragma unroll
            for (int nf = 0; nf < 4; nf++) {
                int col = nf * 16 + l15;
                bf16x8 b = *(const bf16x8*)(Vt + col * 64 + (kg ^ (col & 7)) * 8);
                acc[nf] = __builtin_amdgcn_mfma_f32_16x16x32_bf16(a, b, acc[nf], 0, 0, 0);
            }
        }
    }

    #pragma unroll
    for (int nf = 0; nf < 4; nf++) {
        int d = d0 + nf * 16 + l15;
        #pragma unroll
        for (int reg = 0; reg < 4; reg++) {
            int n = n0 + w * 16 + lg * 4 + reg;
            if (n < nw)
                yw[((long long)bt * nw + n) * dlen + d] = f2bf(acc[nf][reg]);
        }
    }
}

// ---------------- Wo fp32 [o][c][3][3] -> bf16 Wt[t][cc][o][cl]
__global__ __launch_bounds__(256) void transform_w_kernel(const float* __restrict__ Wo,
    unsigned short* __restrict__ Wt)
{
    int idx = blockIdx.x * 256 + threadIdx.x;
    if (idx >= 9 * 8 * 256 * 32) return;
    int cl = idx & 31;
    int o  = (idx >> 5) & 255;
    int cc = (idx >> 13) & 7;
    int t  = idx >> 16;
    int dy = t / 3, dx = t - dy * 3;
    int c = cc * 32 + cl;
    Wt[idx] = f2bf(Wo[((long long)(o * CCH + c) * 3 + dy) * 3 + dx]);
}

// ---------------- 3x3 conv via bf16 MFMA implicit GEMM + bias + LeakyReLU
// Reads the per-head windowed PV outputs directly (d-index = pyx*64 + ch).
__global__ __launch_bounds__(256) void conv_mfma_kernel(
    const unsigned short* __restrict__ ywb_all, const unsigned short* __restrict__ Wt,
    const float* __restrict__ bo, float* __restrict__ out)
{
    __shared__ alignas(16) unsigned short in_t[6 * 104 * 32];   // [row][px][ch32], px-swizzled
    int tid = threadIdx.x;
    int ytile = blockIdx.x, otile = blockIdx.y, bt = blockIdx.z;
    int ybase = ytile * 4, o0 = otile * 64;
    int w = tid >> 6, l = tid & 63;
    int l15 = l & 15, lg = l >> 4;

    f32x4 acc[4][6];
    #pragma unroll
    for (int mf = 0; mf < 4; mf++)
        #pragma unroll
        for (int nf = 0; nf < 6; nf++)
            acc[mf][nf] = (f32x4){0.f, 0.f, 0.f, 0.f};

    for (int it = tid; it < 96; it += 256) {
        int side = it / 48, rem = it - side * 48;
        int row = rem >> 3, cg = rem & 7;
        int px = side ? 97 : 0;
        int byte = (((row * 104 + px) * 64) + cg * 8) ^ ((px & 3) << 4);
        ushort4 z = {0, 0, 0, 0};
        *(ushort4*)((char*)in_t + byte) = z;
    }

    for (int cc = 0; cc < 8; cc++) {
        __syncthreads();
        int h = cc >> 1;
        int lp = h + 1, P = 2 << h;
        int side = 96 >> lp;
        int nwin = side * side;
        long long dlen = 64LL << (2 * lp);
        const unsigned short* yb = ywb_all + (long long)h * WIN
                                 + (long long)bt * nwin * dlen + (cc & 1) * 32;
        for (int it = tid; it < 2304; it += 256) {
            int g = it & 3;
            int xr = (it >> 2) % 96;
            int row = it / 384;
            int ya = ybase + row - 1;
            bf16x8 v = {0,0,0,0,0,0,0,0};
            if (ya >= 0 && ya < IH) {
                int n = (ya >> lp) * side + (xr >> lp);
                int pyx = ((ya & (P - 1)) << lp) + (xr & (P - 1));
                v = *(const bf16x8*)(yb + (long long)n * dlen + pyx * 64 + g * 8);
            }
            int px = xr + 1;
            int byte = ((((row * 104 + px) * 64) + g * 16)) ^ ((px & 3) << 4);
            *(bf16x8*)((char*)in_t + byte) = v;
        }
        __syncthreads();

        for (int t = 0; t < 9; t++) {
            int dy = t / 3, dx = t - dy * 3;
            bf16x8 a[4];
            const unsigned short* wp = Wt + ((long long)(t * 8 + cc) * 256 + o0) * 32 + lg * 8;
            #pragma unroll
            for (int mf = 0; mf < 4; mf++)
                a[mf] = *(const bf16x8*)(wp + (mf * 16 + l15) * 32);
            int rowoff = (w + dy) * 104;
            #pragma unroll
            for (int nf = 0; nf < 6; nf++) {
                int px = nf * 16 + l15 + dx;
                int byte = (((rowoff + px) * 64) + lg * 16) ^ ((px & 3) << 4);
                bf16x8 b = *(const bf16x8*)((const char*)in_t + byte);
                #pragma unroll
                for (int mf = 0; mf < 4; mf++)
                    acc[mf][nf] = __builtin_amdgcn_mfma_f32_16x16x32_bf16(a[mf], b, acc[mf][nf], 0, 0, 0);
            }
        }
    }

    int y = ybase + w;
    #pragma unroll
    for (int mf = 0; mf < 4; mf++) {
        #pragma unroll
        for (int reg = 0; reg < 4; reg++) {
            int o = o0 + mf * 16 + lg * 4 + reg;
            float bv = bo[o];
            long long obase = (((long long)bt * CCH + o) * IH + y) * IW;
            #pragma unroll
            for (int nf = 0; nf < 6; nf++) {
                int x = nf * 16 + l15;
                float v = acc[mf][nf][reg] + bv;
                out[obase + x] = v >= 0.f ? v : 0.2f * v;
            }
        }
    }
}

// ---------------- per-head host driver
template<int P, int LOGP>
static void run_head(const unsigned short* qw, const unsigned short* kw, const unsigned short* vw,
                     unsigned short* ywb, char* scratch, size_t sbud,
                     int head, int ks, hipStream_t stream)
{
    constexpr int SIDE = 96 / P;
    constexpr int NWIN = SIDE * SIDE;
    constexpr int DLEN = DK * P * P;
    int nw = NWIN, dlen = DLEN;
    float scale = 1.0f / sqrtf((float)dlen);
    int nt = (nw + 63) / 64;
    int tspan = nt * 64;
    dim3 blk(256);

    int btc = BT;
    while (btc > 1 && (size_t)btc * nw * nw * 6 + (ks > 1 ? (size_t)btc * ks * tspan * tspan * 4 : 0) > sbud)
        btc >>= 1;

    float* scores = (float*)scratch;
    unsigned short* pb16 = (unsigned short*)(scratch + (size_t)btc * nw * nw * 4);
    float* partial = (float*)(scratch + (((size_t)btc * nw * nw * 6 + 255) & ~(size_t)255));

    for (int bt0 = 0; bt0 < BT; bt0 += btc) {
        qk_mfma_kernel<<<dim3(nt, nt, btc * ks), blk, 0, stream>>>(qw, kw, scores, partial,
                                                                   nw, dlen, scale, ks, tspan, bt0);
        if (ks > 1) {
            long long tot = (long long)btc * nw * nw;
            qk_reduce_kernel<<<(unsigned)((tot + 255) / 256), blk, 0, stream>>>(
                partial, scores, nw, tspan, ks, scale, btc);
        }
        softmax_kernel<<<dim3(nw, btc), blk, 0, stream>>>(scores, pb16, nw);
        pv_mfma_kernel<<<dim3(dlen / 64, nt, btc), blk, 0, stream>>>(pb16, vw, ywb, nw, dlen, bt0);
    }
}

extern "C" void kernel_launch(void* const* d_in, const int* in_sizes, int n_in,
                              void* d_out, int out_size, void* d_ws, size_t ws_size,
                              hipStream_t stream) {
    const float* x  = (const float*)d_in[0];
    const float* x1 = (const float*)d_in[1];
    const float* Wq = (const float*)d_in[2];
    const float* bq = (const float*)d_in[3];
    const float* Wk = (const float*)d_in[4];
    const float* bk = (const float*)d_in[5];
    const float* Wv = (const float*)d_in[6];
    const float* bv = (const float*)d_in[7];
    const float* Wo = (const float*)d_in[8];
    const float* bo = (const float*)d_in[9];
    float* out = (float*)d_out;

    // workspace (u16 elems): xT 4W | x1T 4W | qfull 4W | kfull 4W | vfull 4W | ywb_all 4W
    unsigned short* xT      = (unsigned short*)d_ws;
    unsigned short* x1T     = xT + NFULL;
    unsigned short* qfull   = x1T + NFULL;
    unsigned short* kfull   = qfull + NFULL;
    unsigned short* vfull   = kfull + NFULL;
    unsigned short* ywb_all = vfull + NFULL;
    // overlays:
    unsigned short* Wb = ywb_all;            // 3*65536 u16, dead before pv head0
    char* scratch = (char*)xT;               // 8 WB, dead after proj (scores/pb16/partial)
    unsigned short* Wt = (unsigned short*)scratch;  // conv weights, after heads

    size_t sbud = (size_t)(8 * WB);

    dim3 blk(256);
    cvtw_kernel<<<192, blk, 0, stream>>>(Wq, Wk, Wv, Wb);
    transpose_cvt_kernel<<<dim3(144, 4, BT), blk, 0, stream>>>(x,  xT);
    transpose_cvt_kernel<<<dim3(144, 4, BT), blk, 0, stream>>>(x1, x1T);

    proj_mfma_kernel<1><<<dim3(144, 1, BT), blk, 0, stream>>>(xT,  Wb, bq, qfull, Wb, bq, qfull);
    proj_mfma_kernel<2><<<dim3(144, 1, BT), blk, 0, stream>>>(x1T, Wb + 65536, bk, kfull,
                                                              Wb + 131072, bv, vfull);

    run_head<2, 1>(qfull,           kfull,           vfull,           ywb_all,           (char*)scratch, sbud, 0, 1,  stream);
    run_head<4, 2>(qfull + WIN,     kfull + WIN,     vfull + WIN,     ywb_all + WIN,     (char*)scratch, sbud, 1, 1,  stream);
    run_head<8, 3>(qfull + 2 * WIN, kfull + 2 * WIN, vfull + 2 * WIN, ywb_all + 2 * WIN, (char*)scratch, sbud, 2, 8,  stream);
    run_head<16,4>(qfull + 3 * WIN, kfull + 3 * WIN, vfull + 3 * WIN, ywb_all + 3 * WIN, (char*)scratch, sbud, 3, 64, stream);

    transform_w_kernel<<<(9 * 8 * 256 * 32 + 255) / 256, blk, 0, stream>>>(Wo, Wt);
    conv_mfma_kernel<<<dim3(24, 4, BT), blk, 0, stream>>>(ywb_all, Wt, bo, out);
}

// Round 7
// 1038.140 us; speedup vs baseline: 7.2179x; 1.2260x over previous
//
#include <hip/hip_runtime.h>
#include <math.h>

#define BT 16
#define CCH 256
#define IH 96
#define IW 96
#define HW (IH*IW)            // 9216
#define DK 64

static const long long WIN   = (long long)BT * HW * DK;   // 9,437,184 elems (one head, all bt)
static const long long NFULL = 4 * WIN;                    // 37,748,736 elems
static const long long WB    = WIN * 2;                    // bytes of one bf16 head buffer

typedef __attribute__((ext_vector_type(8))) short bf16x8;
typedef __attribute__((ext_vector_type(4))) float f32x4;

__device__ __forceinline__ unsigned short f2bf(float f) {
    unsigned int x = __float_as_uint(f);
    unsigned int r = (x + 0x7FFFu + ((x >> 16) & 1u)) >> 16;
    return (unsigned short)r;
}

// ---------------- transpose+convert: x[bt][c][hw] fp32 -> xT[bt][hw][c] bf16
__global__ __launch_bounds__(256) void transpose_cvt_kernel(const float* __restrict__ x,
    unsigned short* __restrict__ xT)
{
    __shared__ float Ls[64][65];
    int tid = threadIdx.x;
    int p0 = blockIdx.x * 64;
    int c0 = blockIdx.y * 64;
    int bt = blockIdx.z;
    int px4 = (tid & 15) * 4, chb = tid >> 4;
    const float* xb = x + ((long long)(bt * CCH + c0) * HW) + p0;
    #pragma unroll
    for (int it = 0; it < 4; it++) {
        int ch = chb + it * 16;
        float4 v = *(const float4*)(xb + (long long)ch * HW + px4);
        Ls[px4 + 0][ch] = v.x;
        Ls[px4 + 1][ch] = v.y;
        Ls[px4 + 2][ch] = v.z;
        Ls[px4 + 3][ch] = v.w;
    }
    __syncthreads();
    int px = tid >> 2, cg = (tid & 3) * 16;
    unsigned short* dst = xT + ((long long)bt * HW + p0 + px) * CCH + c0 + cg;
    #pragma unroll
    for (int half = 0; half < 2; half++) {
        ushort4 a, b;
        a.x = f2bf(Ls[px][cg + half * 8 + 0]);
        a.y = f2bf(Ls[px][cg + half * 8 + 1]);
        a.z = f2bf(Ls[px][cg + half * 8 + 2]);
        a.w = f2bf(Ls[px][cg + half * 8 + 3]);
        b.x = f2bf(Ls[px][cg + half * 8 + 4]);
        b.y = f2bf(Ls[px][cg + half * 8 + 5]);
        b.z = f2bf(Ls[px][cg + half * 8 + 6]);
        b.w = f2bf(Ls[px][cg + half * 8 + 7]);
        *(ushort4*)(dst + half * 8)     = a;
        *(ushort4*)(dst + half * 8 + 4) = b;
    }
}

// ---------------- Wq/Wk/Wv fp32 -> bf16 (same [o][c] layout), packed [3][256][256]
__global__ __launch_bounds__(256) void cvtw_kernel(const float* __restrict__ Wq,
    const float* __restrict__ Wk, const float* __restrict__ Wv,
    unsigned short* __restrict__ Wb)
{
    int idx = blockIdx.x * 256 + threadIdx.x;
    if (idx >= 3 * 16384) return;
    const float* src = idx < 16384 ? Wq : (idx < 32768 ? Wk : Wv);
    int off = (idx & 16383) * 4;
    float4 v = *(const float4*)(src + off);
    ushort4 u = {f2bf(v.x), f2bf(v.y), f2bf(v.z), f2bf(v.w)};
    *(ushort4*)(Wb + (long long)idx * 4) = u;
}

// ---------------- fused 1x1-conv projections via bf16 MFMA (bf16 inputs)
template<int NPASS>
__global__ __launch_bounds__(256) void proj_mfma_kernel(
    const unsigned short* __restrict__ xT,
    const unsigned short* __restrict__ Wb0, const float* __restrict__ b0, unsigned short* __restrict__ o0p,
    const unsigned short* __restrict__ Wb1, const float* __restrict__ b1, unsigned short* __restrict__ o1p)
{
    __shared__ alignas(16) unsigned short Xs[64 * 256];
    __shared__ alignas(16) unsigned short Ws[256 * 64];
    int tid = threadIdx.x;
    int p0 = blockIdx.x * 64;
    int bt = blockIdx.z;
    int w = tid >> 6, l = tid & 63, l15 = l & 15, lg = l >> 4;

    {
        const unsigned short* xb = xT + ((long long)bt * HW + p0) * CCH;
        #pragma unroll
        for (int it = 0; it < 8; it++) {
            int flat = tid + it * 256;
            int px = flat >> 5, cg = flat & 31;
            bf16x8 v = *(const bf16x8*)(xb + (long long)px * CCH + cg * 8);
            *(bf16x8*)((char*)Xs + px * 512 + ((cg ^ (px & 31)) << 4)) = v;
        }
    }

    for (int pass = 0; pass < NPASS; pass++) {
        const unsigned short* W = pass ? Wb1 : Wb0;
        const float* bias = pass ? b1 : b0;
        unsigned short* outp = pass ? o1p : o0p;

        f32x4 acc[4][4];
        #pragma unroll
        for (int i = 0; i < 4; i++)
            #pragma unroll
            for (int j = 0; j < 4; j++) acc[i][j] = (f32x4){0.f, 0.f, 0.f, 0.f};

        for (int kc = 0; kc < CCH; kc += 64) {
            __syncthreads();
            #pragma unroll
            for (int it = 0; it < 8; it++) {
                int flat = tid + it * 256;
                int o = flat >> 3, kg = flat & 7;
                bf16x8 v = *(const bf16x8*)(W + o * 256 + kc + kg * 8);
                *(bf16x8*)((char*)Ws + o * 128 + ((kg ^ (o & 7)) << 4)) = v;
            }
            __syncthreads();
            #pragma unroll
            for (int kst = 0; kst < 2; kst++) {
                bf16x8 a[4], b[4];
                #pragma unroll
                for (int mf = 0; mf < 4; mf++) {
                    int m = w * 64 + mf * 16 + l15;
                    int uu = (kst * 4 + lg) ^ (m & 7);
                    a[mf] = *(const bf16x8*)((const char*)Ws + m * 128 + (uu << 4));
                }
                #pragma unroll
                for (int nf = 0; nf < 4; nf++) {
                    int px = nf * 16 + l15;
                    int ug = (kc >> 3) + kst * 4 + lg;
                    b[nf] = *(const bf16x8*)((const char*)Xs + px * 512 + ((ug ^ (px & 31)) << 4));
                }
                #pragma unroll
                for (int mf = 0; mf < 4; mf++)
                    #pragma unroll
                    for (int nf = 0; nf < 4; nf++)
                        acc[mf][nf] = __builtin_amdgcn_mfma_f32_16x16x32_bf16(a[mf], b[nf], acc[mf][nf], 0, 0, 0);
            }
        }

        __syncthreads();
        #pragma unroll
        for (int mf = 0; mf < 4; mf++) {
            int ch0 = w * 64 + mf * 16 + lg * 4;
            float4 bv = *(const float4*)(bias + ch0);
            #pragma unroll
            for (int nf = 0; nf < 4; nf++) {
                int px = nf * 16 + l15;
                ushort4 u4 = {f2bf(acc[mf][nf][0] + bv.x), f2bf(acc[mf][nf][1] + bv.y),
                              f2bf(acc[mf][nf][2] + bv.z), f2bf(acc[mf][nf][3] + bv.w)};
                int uu = (ch0 >> 3) ^ (px & 31);
                *(ushort4*)((char*)Ws + px * 512 + (uu << 4) + ((ch0 >> 2) & 1) * 8) = u4;
            }
        }
        __syncthreads();
        {
            int cg = tid & 31;
            int h = cg >> 3, lp = h + 1, P = 2 << h;
            int side = 96 >> lp;
            int nwin = side * side;
            long long dlen = (long long)64 << (2 * lp);
            unsigned short* dst = outp + (long long)h * WIN + (long long)bt * nwin * dlen + (cg & 7) * 8;
            #pragma unroll
            for (int it = 0; it < 8; it++) {
                int pxl = it * 8 + (tid >> 5);
                int p = p0 + pxl;
                int y = p / 96, xx = p - y * 96;
                int n = (y >> lp) * side + (xx >> lp);
                int pyx = ((y & (P - 1)) << lp) + (xx & (P - 1));
                int uu = cg ^ (pxl & 31);
                bf16x8 v = *(const bf16x8*)((const char*)Ws + pxl * 512 + (uu << 4));
                *(bf16x8*)(dst + (long long)n * dlen + (long long)pyx * 64) = v;
            }
        }
    }
}

// ---------------- head 0 flash attention: nw=2304, d=256, one kernel
__global__ __launch_bounds__(256, 2) void flash0_kernel(
    const unsigned short* __restrict__ q, const unsigned short* __restrict__ k,
    const unsigned short* __restrict__ v, unsigned short* __restrict__ o)
{
    constexpr int NW = 2304, D = 256;
    __shared__ alignas(16) unsigned short KV[64 * 256];  // 32KB: K tile, then V^T tile
    __shared__ alignas(16) unsigned short Ps[64 * 64];   // 8KB P (per-wave 16-row slices)
    int tid = threadIdx.x;
    int w = tid >> 6, l = tid & 63, l15 = l & 15, lg = l >> 4;
    int q0 = blockIdx.x * 64;
    int bt = blockIdx.y;
    const unsigned short* qb = q + ((long long)bt * NW + q0) * D;
    const unsigned short* kb = k + (long long)bt * NW * D;
    const unsigned short* vb = v + (long long)bt * NW * D;
    const float scale = 1.0f / 16.0f;

    // Q fragments in registers: row = w*16 + l15, frag i covers k = i*32 + lg*8 + j
    bf16x8 qf[8];
    #pragma unroll
    for (int i = 0; i < 8; i++)
        qf[i] = *(const bf16x8*)(qb + (long long)(w * 16 + l15) * D + i * 32 + lg * 8);

    f32x4 Oacc[16];
    #pragma unroll
    for (int i = 0; i < 16; i++) Oacc[i] = (f32x4){0.f, 0.f, 0.f, 0.f};
    float mrow[4] = {-3e38f, -3e38f, -3e38f, -3e38f};
    float srow[4] = {0.f, 0.f, 0.f, 0.f};

    for (int mt = 0; mt < NW; mt += 64) {
        __syncthreads();                       // KV buffer free (prev PV done)
        // ---- stage K tile [64 m][256 k]
        #pragma unroll
        for (int it = 0; it < 8; it++) {
            int flat = tid + it * 256;
            int row = flat >> 5, kg = flat & 31;
            bf16x8 kv8 = *(const bf16x8*)(kb + (long long)(mt + row) * D + kg * 8);
            int u = (kg & 24) | ((kg ^ row) & 7);
            *(bf16x8*)((char*)KV + row * 512 + (u << 4)) = kv8;
        }
        __syncthreads();
        // ---- QK^T: S rows = lg*4+reg (q), cols = nf*16+l15 (kv)
        f32x4 s[4];
        #pragma unroll
        for (int nf = 0; nf < 4; nf++) s[nf] = (f32x4){0.f, 0.f, 0.f, 0.f};
        #pragma unroll
        for (int i = 0; i < 8; i++) {
            int kgu = i * 4 + lg;
            #pragma unroll
            for (int nf = 0; nf < 4; nf++) {
                int m = nf * 16 + l15;
                int u = (kgu & 24) | ((kgu ^ m) & 7);
                bf16x8 b = *(const bf16x8*)((const char*)KV + m * 512 + (u << 4));
                s[nf] = __builtin_amdgcn_mfma_f32_16x16x32_bf16(qf[i], b, s[nf], 0, 0, 0);
            }
        }
        // ---- online softmax
        float pmax[4];
        #pragma unroll
        for (int reg = 0; reg < 4; reg++) {
            float mx = -3e38f;
            #pragma unroll
            for (int nf = 0; nf < 4; nf++) { s[nf][reg] *= scale; mx = fmaxf(mx, s[nf][reg]); }
            pmax[reg] = mx;
        }
        #pragma unroll
        for (int d = 1; d < 16; d <<= 1)
            #pragma unroll
            for (int reg = 0; reg < 4; reg++)
                pmax[reg] = fmaxf(pmax[reg], __shfl_xor(pmax[reg], d, 64));
        bool grow = (pmax[0] > mrow[0]) || (pmax[1] > mrow[1]) ||
                    (pmax[2] > mrow[2]) || (pmax[3] > mrow[3]);
        if (__any(grow)) {
            float corr[4];
            #pragma unroll
            for (int reg = 0; reg < 4; reg++) {
                float mnew = fmaxf(mrow[reg], pmax[reg]);
                corr[reg] = __expf(mrow[reg] - mnew);
                mrow[reg] = mnew;
                srow[reg] *= corr[reg];
            }
            #pragma unroll
            for (int nf2 = 0; nf2 < 16; nf2++)
                #pragma unroll
                for (int reg = 0; reg < 4; reg++)
                    Oacc[nf2][reg] *= corr[reg];
        }
        float psum[4] = {0.f, 0.f, 0.f, 0.f};
        #pragma unroll
        for (int nf = 0; nf < 4; nf++) {
            #pragma unroll
            for (int reg = 0; reg < 4; reg++) {
                float p = __expf(s[nf][reg] - mrow[reg]);
                psum[reg] += p;
                int qr = lg * 4 + reg;
                int kvc = nf * 16 + l15;
                int u = ((kvc >> 3) ^ (qr & 7)) & 7;
                *((unsigned short*)((char*)Ps + w * 2048 + qr * 128 + (u << 4) + (kvc & 7) * 2)) = f2bf(p);
            }
        }
        #pragma unroll
        for (int d = 1; d < 16; d <<= 1)
            #pragma unroll
            for (int reg = 0; reg < 4; reg++)
                psum[reg] += __shfl_xor(psum[reg], d, 64);
        #pragma unroll
        for (int reg = 0; reg < 4; reg++) srow[reg] += psum[reg];
        __syncthreads();                       // QK reads done, P visible
        // ---- stage V^T tile: Vt[256 d][64 m] over KV buffer
        {
            int du = tid & 15, mu = tid >> 4;  // mu 0..15
            #pragma unroll
            for (int dblk = 0; dblk < 4; dblk++) {
                int due = dblk * 16 + du;
                ushort4 vv[4];
                #pragma unroll
                for (int i = 0; i < 4; i++)
                    vv[i] = *(const ushort4*)(vb + (long long)(mt + mu * 4 + i) * D + due * 4);
                #pragma unroll
                for (int j = 0; j < 4; j++) {
                    int dd = due * 4 + j;
                    int byte = dd * 128 + ((((mu >> 1) ^ (dd & 7)) & 7) << 4) + (mu & 1) * 8;
                    ushort4 tj;
                    tj.x = ((const unsigned short*)&vv[0])[j];
                    tj.y = ((const unsigned short*)&vv[1])[j];
                    tj.z = ((const unsigned short*)&vv[2])[j];
                    tj.w = ((const unsigned short*)&vv[3])[j];
                    *(ushort4*)((char*)KV + byte) = tj;
                }
            }
        }
        __syncthreads();
        // ---- PV: A = P (own wave slice), B = Vt
        bf16x8 pa[2];
        #pragma unroll
        for (int kc = 0; kc < 2; kc++) {
            int kg = kc * 4 + lg;
            int u = (kg ^ (l15 & 7)) & 7;
            pa[kc] = *(const bf16x8*)((const char*)Ps + w * 2048 + l15 * 128 + (u << 4));
        }
        #pragma unroll
        for (int nf2 = 0; nf2 < 16; nf2++) {
            int dd = nf2 * 16 + l15;
            #pragma unroll
            for (int kc = 0; kc < 2; kc++) {
                int kg = kc * 4 + lg;
                int u = (kg ^ (dd & 7)) & 7;
                bf16x8 b = *(const bf16x8*)((const char*)KV + dd * 128 + (u << 4));
                Oacc[nf2] = __builtin_amdgcn_mfma_f32_16x16x32_bf16(pa[kc], b, Oacc[nf2], 0, 0, 0);
            }
        }
    }
    // ---- epilogue: normalize, write bf16
    unsigned short* ob = o + ((long long)bt * NW + q0) * D;
    #pragma unroll
    for (int reg = 0; reg < 4; reg++) {
        float inv = 1.f / srow[reg];
        int qr = w * 16 + lg * 4 + reg;
        #pragma unroll
        for (int nf2 = 0; nf2 < 16; nf2++) {
            int dd = nf2 * 16 + l15;
            ob[(long long)qr * D + dd] = f2bf(Oacc[nf2][reg] * inv);
        }
    }
}

// ---------------- QK^T via bf16 MFMA, 64x64 tile, optional split-K (heads 1-3)
__global__ __launch_bounds__(256) void qk_mfma_kernel(const unsigned short* __restrict__ qw,
    const unsigned short* __restrict__ kw, float* __restrict__ scores,
    float* __restrict__ partial, int nw, int dlen, float scale, int ksplit,
    int tspan, int bt0)
{
    __shared__ alignas(16) unsigned short Qs[64 * 64];
    __shared__ alignas(16) unsigned short Ks[64 * 64];
    int tid = threadIdx.x;
    int m0 = blockIdx.x * 64, n0 = blockIdx.y * 64;
    int btl = blockIdx.z / ksplit;
    int kidx = blockIdx.z - btl * ksplit;
    int bt = bt0 + btl;
    int dchunk = dlen / ksplit;
    long long kbase = (long long)kidx * dchunk;
    int w = tid >> 6, l = tid & 63, l15 = l & 15, lg = l >> 4;
    f32x4 acc[4];
    #pragma unroll
    for (int nf = 0; nf < 4; nf++) acc[nf] = (f32x4){0.f, 0.f, 0.f, 0.f};

    const unsigned short* qb = qw + ((long long)bt * nw + n0) * dlen + kbase;
    const unsigned short* kb = kw + ((long long)bt * nw + m0) * dlen + kbase;
    int qrows = nw - n0; if (qrows > 64) qrows = 64;
    int krows = nw - m0; if (krows > 64) krows = 64;
    int arow = w * 16 + l15;

    for (int kc = 0; kc < dchunk; kc += 64) {
        if (kc) __syncthreads();
        #pragma unroll
        for (int i = 0; i < 2; i++) {
            int c = tid + i * 256;
            int row = c >> 3, kg = c & 7;
            int kgs = (kg ^ (row & 7)) * 8;
            bf16x8 qv = {0,0,0,0,0,0,0,0};
            bf16x8 kv = {0,0,0,0,0,0,0,0};
            if (row < qrows) qv = *(const bf16x8*)(qb + (long long)row * dlen + kc + kg * 8);
            if (row < krows) kv = *(const bf16x8*)(kb + (long long)row * dlen + kc + kg * 8);
            *(bf16x8*)(Qs + row * 64 + kgs) = qv;
            *(bf16x8*)(Ks + row * 64 + kgs) = kv;
        }
        __syncthreads();
        #pragma unroll
        for (int k0 = 0; k0 < 64; k0 += 32) {
            int kg = (k0 >> 3) + lg;
            bf16x8 a = *(const bf16x8*)(Qs + arow * 64 + (kg ^ (arow & 7)) * 8);
            #pragma unroll
            for (int nf = 0; nf < 4; nf++) {
                int col = nf * 16 + l15;
                bf16x8 b = *(const bf16x8*)(Ks + col * 64 + (kg ^ (col & 7)) * 8);
                acc[nf] = __builtin_amdgcn_mfma_f32_16x16x32_bf16(a, b, acc[nf], 0, 0, 0);
            }
        }
    }

    if (ksplit == 1) {
        #pragma unroll
        for (int nf = 0; nf < 4; nf++) {
            int c = m0 + nf * 16 + l15;
            #pragma unroll
            for (int reg = 0; reg < 4; reg++) {
                int r = n0 + w * 16 + lg * 4 + reg;
                if (r < nw && c < nw)
                    scores[((long long)btl * nw + r) * nw + c] = acc[nf][reg] * scale;
            }
        }
    } else {
        #pragma unroll
        for (int nf = 0; nf < 4; nf++) {
            int c = m0 + nf * 16 + l15;
            #pragma unroll
            for (int reg = 0; reg < 4; reg++) {
                int r = n0 + w * 16 + lg * 4 + reg;
                partial[(((long long)btl * ksplit + kidx) * tspan + r) * tspan + c] = acc[nf][reg];
            }
        }
    }
}

__global__ __launch_bounds__(256) void qk_reduce_kernel(const float* __restrict__ partial,
    float* __restrict__ scores, int nw, int tspan, int ksplit, float scale, int btc)
{
    long long idx = (long long)blockIdx.x * 256 + threadIdx.x;
    if (idx >= (long long)btc * nw * nw) return;
    int m = (int)(idx % nw);
    long long t = idx / nw;
    int n = (int)(t % nw);
    int btl = (int)(t / nw);
    float s = 0.f;
    for (int k = 0; k < ksplit; k++)
        s += partial[(((long long)btl * ksplit + k) * tspan + n) * tspan + m];
    scores[((long long)btl * nw + n) * nw + m] = s * scale;
}

// ---------------- row softmax: fp32 scores in, bf16 P out
__global__ __launch_bounds__(256) void softmax_kernel(const float* __restrict__ scores,
    unsigned short* __restrict__ pb16, int nw)
{
    __shared__ float red[8];
    int n = blockIdx.x, btl = blockIdx.y;
    const float* row = scores + ((long long)btl * nw + n) * nw;
    unsigned short* prow = pb16 + ((long long)btl * nw + n) * nw;
    int tid = threadIdx.x;
    float vals[9];
    float lmax = -3e38f;
    #pragma unroll
    for (int it = 0; it < 9; it++) {
        int m = tid + it * 256;
        if (m < nw) { vals[it] = row[m]; lmax = fmaxf(lmax, vals[it]); }
        else vals[it] = -3e38f;
    }
    #pragma unroll
    for (int o = 32; o > 0; o >>= 1) lmax = fmaxf(lmax, __shfl_down(lmax, o, 64));
    if ((tid & 63) == 0) red[tid >> 6] = lmax;
    __syncthreads();
    float rmax = fmaxf(fmaxf(red[0], red[1]), fmaxf(red[2], red[3]));
    __syncthreads();
    float lsum = 0.f;
    #pragma unroll
    for (int it = 0; it < 9; it++) {
        int m = tid + it * 256;
        if (m < nw) { vals[it] = __expf(vals[it] - rmax); lsum += vals[it]; }
    }
    #pragma unroll
    for (int o = 32; o > 0; o >>= 1) lsum += __shfl_down(lsum, o, 64);
    if ((tid & 63) == 0) red[tid >> 6] = lsum;
    __syncthreads();
    float rsum = red[0] + red[1] + red[2] + red[3];
    float inv = 1.f / rsum;
    #pragma unroll
    for (int it = 0; it < 9; it++) {
        int m = tid + it * 256;
        if (m < nw) prow[m] = f2bf(vals[it] * inv);
    }
}

// ---------------- P @ V via bf16 MFMA; 64(n) x 64(d) tile, bf16 output
__global__ __launch_bounds__(256) void pv_mfma_kernel(const unsigned short* __restrict__ p,
    const unsigned short* __restrict__ vw, unsigned short* __restrict__ yw, int nw, int dlen, int bt0)
{
    __shared__ alignas(16) unsigned short Ps[64 * 64];
    __shared__ alignas(16) unsigned short Vt[64 * 64];
    int tid = threadIdx.x;
    int d0 = blockIdx.x * 64, n0 = blockIdx.y * 64;
    int btl = blockIdx.z;
    int bt = bt0 + btl;
    int w = tid >> 6, l = tid & 63, l15 = l & 15, lg = l >> 4;
    f32x4 acc[4];
    #pragma unroll
    for (int nf = 0; nf < 4; nf++) acc[nf] = (f32x4){0.f, 0.f, 0.f, 0.f};

    const unsigned short* pb = p + ((long long)btl * nw + n0) * nw;
    const unsigned short* vb = vw + (long long)bt * nw * dlen + d0;
    int prows = nw - n0; if (prows > 64) prows = 64;
    int arow = w * 16 + l15;
    int du = tid & 15, mu = tid >> 4;

    for (int mc = 0; mc < nw; mc += 64) {
        if (mc) __syncthreads();
        int mrem = nw - mc;
        #pragma unroll
        for (int i = 0; i < 2; i++) {
            int c = tid + i * 256;
            int row = c >> 3, kg = c & 7;
            bf16x8 v = {0,0,0,0,0,0,0,0};
            if (row < prows) {
                int mb = kg * 8;
                if (mb + 8 <= mrem) v = *(const bf16x8*)(pb + (long long)row * nw + mc + mb);
                else if (mb < mrem) {
                    for (int e = 0; e < mrem - mb; e++)
                        v[e] = (short)pb[(long long)row * nw + mc + mb + e];
                }
            }
            *(bf16x8*)(Ps + row * 64 + (kg ^ (row & 7)) * 8) = v;
        }
        {
            ushort4 vv[4];
            #pragma unroll
            for (int i = 0; i < 4; i++) {
                int m = mc + mu * 4 + i;
                if (m < nw) vv[i] = *(const ushort4*)(vb + (long long)m * dlen + du * 4);
                else vv[i] = (ushort4){0, 0, 0, 0};
            }
            #pragma unroll
            for (int j = 0; j < 4; j++) {
                int d = du * 4 + j;
                int byte = d * 128 + (((mu >> 1) ^ (d & 7)) * 16) + (mu & 1) * 8;
                ushort4 tj;
                tj.x = ((const unsigned short*)&vv[0])[j];
                tj.y = ((const unsigned short*)&vv[1])[j];
                tj.z = ((const unsigned short*)&vv[2])[j];
                tj.w = ((const unsigned short*)&vv[3])[j];
                *(ushort4*)((char*)Vt + byte) = tj;
            }
        }
        __syncthreads();
        #pragma unroll
        for (int k0 = 0; k0 < 64; k0 += 32) {
            int kg = (k0 >> 3) + lg;
            bf16x8 a = *(const bf16x8*)(Ps + arow * 64 + (kg ^ (arow & 7)) * 8);
            #pragma unroll
            for (int nf = 0; nf < 4; nf++) {
                int col = nf * 16 + l15;
                bf16x8 b = *(const bf16x8*)(Vt + col * 64 + (kg ^ (col & 7)) * 8);
                acc[nf] = __builtin_amdgcn_mfma_f32_16x16x32_bf16(a, b, acc[nf], 0, 0, 0);
            }
        }
    }

    #pragma unroll
    for (int nf = 0; nf < 4; nf++) {
        int d = d0 + nf * 16 + l15;
        #pragma unroll
        for (int reg = 0; reg < 4; reg++) {
            int n = n0 + w * 16 + lg * 4 + reg;
            if (n < nw)
                yw[((long long)bt * nw + n) * dlen + d] = f2bf(acc[nf][reg]);
        }
    }
}

// ---------------- Wo fp32 [o][c][3][3] -> bf16 Wt[t][cc][o][cl]
__global__ __launch_bounds__(256) void transform_w_kernel(const float* __restrict__ Wo,
    unsigned short* __restrict__ Wt)
{
    int idx = blockIdx.x * 256 + threadIdx.x;
    if (idx >= 9 * 8 * 256 * 32) return;
    int cl = idx & 31;
    int o  = (idx >> 5) & 255;
    int cc = (idx >> 13) & 7;
    int t  = idx >> 16;
    int dy = t / 3, dx = t - dy * 3;
    int c = cc * 32 + cl;
    Wt[idx] = f2bf(Wo[((long long)(o * CCH + c) * 3 + dy) * 3 + dx]);
}

// ---------------- 3x3 conv via bf16 MFMA implicit GEMM + bias + LeakyReLU
__global__ __launch_bounds__(256) void conv_mfma_kernel(
    const unsigned short* __restrict__ ywb_all, const unsigned short* __restrict__ Wt,
    const float* __restrict__ bo, float* __restrict__ out)
{
    __shared__ alignas(16) unsigned short in_t[6 * 104 * 32];
    int tid = threadIdx.x;
    int ytile = blockIdx.x, otile = blockIdx.y, bt = blockIdx.z;
    int ybase = ytile * 4, o0 = otile * 64;
    int w = tid >> 6, l = tid & 63;
    int l15 = l & 15, lg = l >> 4;

    f32x4 acc[4][6];
    #pragma unroll
    for (int mf = 0; mf < 4; mf++)
        #pragma unroll
        for (int nf = 0; nf < 6; nf++)
            acc[mf][nf] = (f32x4){0.f, 0.f, 0.f, 0.f};

    for (int it = tid; it < 96; it += 256) {
        int side = it / 48, rem = it - side * 48;
        int row = rem >> 3, cg = rem & 7;
        int px = side ? 97 : 0;
        int byte = (((row * 104 + px) * 64) + cg * 8) ^ ((px & 3) << 4);
        ushort4 z = {0, 0, 0, 0};
        *(ushort4*)((char*)in_t + byte) = z;
    }

    for (int cc = 0; cc < 8; cc++) {
        __syncthreads();
        int h = cc >> 1;
        int lp = h + 1, P = 2 << h;
        int side = 96 >> lp;
        int nwin = side * side;
        long long dlen = 64LL << (2 * lp);
        const unsigned short* yb = ywb_all + (long long)h * WIN
                                 + (long long)bt * nwin * dlen + (cc & 1) * 32;
        for (int it = tid; it < 2304; it += 256) {
            int g = it & 3;
            int xr = (it >> 2) % 96;
            int row = it / 384;
            int ya = ybase + row - 1;
            bf16x8 v = {0,0,0,0,0,0,0,0};
            if (ya >= 0 && ya < IH) {
                int n = (ya >> lp) * side + (xr >> lp);
                int pyx = ((ya & (P - 1)) << lp) + (xr & (P - 1));
                v = *(const bf16x8*)(yb + (long long)n * dlen + pyx * 64 + g * 8);
            }
            int px = xr + 1;
            int byte = ((((row * 104 + px) * 64) + g * 16)) ^ ((px & 3) << 4);
            *(bf16x8*)((char*)in_t + byte) = v;
        }
        __syncthreads();

        for (int t = 0; t < 9; t++) {
            int dy = t / 3, dx = t - dy * 3;
            bf16x8 a[4];
            const unsigned short* wp = Wt + ((long long)(t * 8 + cc) * 256 + o0) * 32 + lg * 8;
            #pragma unroll
            for (int mf = 0; mf < 4; mf++)
                a[mf] = *(const bf16x8*)(wp + (mf * 16 + l15) * 32);
            int rowoff = (w + dy) * 104;
            #pragma unroll
            for (int nf = 0; nf < 6; nf++) {
                int px = nf * 16 + l15 + dx;
                int byte = (((rowoff + px) * 64) + lg * 16) ^ ((px & 3) << 4);
                bf16x8 b = *(const bf16x8*)((const char*)in_t + byte);
                #pragma unroll
                for (int mf = 0; mf < 4; mf++)
                    acc[mf][nf] = __builtin_amdgcn_mfma_f32_16x16x32_bf16(a[mf], b, acc[mf][nf], 0, 0, 0);
            }
        }
    }

    int y = ybase + w;
    #pragma unroll
    for (int mf = 0; mf < 4; mf++) {
        #pragma unroll
        for (int reg = 0; reg < 4; reg++) {
            int o = o0 + mf * 16 + lg * 4 + reg;
            float bv = bo[o];
            long long obase = (((long long)bt * CCH + o) * IH + y) * IW;
            #pragma unroll
            for (int nf = 0; nf < 6; nf++) {
                int x = nf * 16 + l15;
                float v = acc[mf][nf][reg] + bv;
                out[obase + x] = v >= 0.f ? v : 0.2f * v;
            }
        }
    }
}

// ---------------- per-head host driver (heads 1-3)
template<int P, int LOGP>
static void run_head(const unsigned short* qw, const unsigned short* kw, const unsigned short* vw,
                     unsigned short* ywb, char* scratch, size_t sbud,
                     int head, int ks, hipStream_t stream)
{
    constexpr int SIDE = 96 / P;
    constexpr int NWIN = SIDE * SIDE;
    constexpr int DLEN = DK * P * P;
    int nw = NWIN, dlen = DLEN;
    float scale = 1.0f / sqrtf((float)dlen);
    int nt = (nw + 63) / 64;
    int tspan = nt * 64;
    dim3 blk(256);

    int btc = BT;
    while (btc > 1 && (size_t)btc * nw * nw * 6 + (ks > 1 ? (size_t)btc * ks * tspan * tspan * 4 : 0) > sbud)
        btc >>= 1;

    float* scores = (float*)scratch;
    unsigned short* pb16 = (unsigned short*)(scratch + (size_t)btc * nw * nw * 4);
    float* partial = (float*)(scratch + (((size_t)btc * nw * nw * 6 + 255) & ~(size_t)255));

    for (int bt0 = 0; bt0 < BT; bt0 += btc) {
        qk_mfma_kernel<<<dim3(nt, nt, btc * ks), blk, 0, stream>>>(qw, kw, scores, partial,
                                                                   nw, dlen, scale, ks, tspan, bt0);
        if (ks > 1) {
            long long tot = (long long)btc * nw * nw;
            qk_reduce_kernel<<<(unsigned)((tot + 255) / 256), blk, 0, stream>>>(
                partial, scores, nw, tspan, ks, scale, btc);
        }
        softmax_kernel<<<dim3(nw, btc), blk, 0, stream>>>(scores, pb16, nw);
        pv_mfma_kernel<<<dim3(dlen / 64, nt, btc), blk, 0, stream>>>(pb16, vw, ywb, nw, dlen, bt0);
    }
}

extern "C" void kernel_launch(void* const* d_in, const int* in_sizes, int n_in,
                              void* d_out, int out_size, void* d_ws, size_t ws_size,
                              hipStream_t stream) {
    const float* x  = (const float*)d_in[0];
    const float* x1 = (const float*)d_in[1];
    const float* Wq = (const float*)d_in[2];
    const float* bq = (const float*)d_in[3];
    const float* Wk = (const float*)d_in[4];
    const float* bk = (const float*)d_in[5];
    const float* Wv = (const float*)d_in[6];
    const float* bv = (const float*)d_in[7];
    const float* Wo = (const float*)d_in[8];
    const float* bo = (const float*)d_in[9];
    float* out = (float*)d_out;

    // workspace (u16 elems): xT 4W | x1T 4W | qfull 4W | kfull 4W | vfull 4W | ywb_all 4W
    unsigned short* xT      = (unsigned short*)d_ws;
    unsigned short* x1T     = xT + NFULL;
    unsigned short* qfull   = x1T + NFULL;
    unsigned short* kfull   = qfull + NFULL;
    unsigned short* vfull   = kfull + NFULL;
    unsigned short* ywb_all = vfull + NFULL;
    // overlays:
    unsigned short* Wb = ywb_all;            // 3*65536 u16, dead before head0 writes ywb... (used only pre-proj)
    char* scratch = (char*)xT;               // 8 WB, dead after proj (scores/pb16/partial)
    unsigned short* Wt = (unsigned short*)scratch;  // conv weights, after heads

    size_t sbud = (size_t)(8 * WB);

    dim3 blk(256);
    cvtw_kernel<<<192, blk, 0, stream>>>(Wq, Wk, Wv, Wb);
    transpose_cvt_kernel<<<dim3(144, 4, BT), blk, 0, stream>>>(x,  xT);
    transpose_cvt_kernel<<<dim3(144, 4, BT), blk, 0, stream>>>(x1, x1T);

    proj_mfma_kernel<1><<<dim3(144, 1, BT), blk, 0, stream>>>(xT,  Wb, bq, qfull, Wb, bq, qfull);
    proj_mfma_kernel<2><<<dim3(144, 1, BT), blk, 0, stream>>>(x1T, Wb + 65536, bk, kfull,
                                                              Wb + 131072, bv, vfull);

    // head 0: single flash-attention kernel (writes ywb_all[0..WIN))
    flash0_kernel<<<dim3(36, BT), blk, 0, stream>>>(qfull, kfull, vfull, ywb_all);

    run_head<4, 2>(qfull + WIN,     kfull + WIN,     vfull + WIN,     ywb_all + WIN,     scratch, sbud, 1, 1,  stream);
    run_head<8, 3>(qfull + 2 * WIN, kfull + 2 * WIN, vfull + 2 * WIN, ywb_all + 2 * WIN, scratch, sbud, 2, 8,  stream);
    run_head<16,4>(qfull + 3 * WIN, kfull + 3 * WIN, vfull + 3 * WIN, ywb_all + 3 * WIN, scratch, sbud, 3, 64, stream);

    transform_w_kernel<<<(9 * 8 * 256 * 32 + 255) / 256, blk, 0, stream>>>(Wo, Wt);
    conv_mfma_kernel<<<dim3(24, 4, BT), blk, 0, stream>>>(ywb_all, Wt, bo, out);
}